// Round 6
// baseline (246.955 us; speedup 1.0000x reference)
//
#include <hip/hip_runtime.h>
#include <math.h>

#define EMB 128
#define MAXEV 4096

struct Hdr { int nl0; int ncomp; };

__device__ __forceinline__ float sigmoidf_(float x) { return 1.0f / (1.0f + expf(-x)); }
__device__ __forceinline__ float softplusf_(float x) {
    return (x > 0.f) ? x + log1pf(expf(-x)) : log1pf(expf(x));
}

// ---------------------------------------------------------------------------
// Kernel 1: most recent earlier event with same user / item id.
// ---------------------------------------------------------------------------
__global__ __launch_bounds__(64) void prev_kernel(
    const int* __restrict__ uids, const int* __restrict__ iids,
    int* __restrict__ prevu, int* __restrict__ previ, int nev)
{
    int t = blockIdx.x;
    if (t >= nev) return;
    int lane = threadIdx.x;
    int myu = uids[t], myi = iids[t];
    int bu = -1, bi = -1;
    for (int j = lane; j < t; j += 64) {
        if (uids[j] == myu) bu = j;
        if (iids[j] == myi) bi = j;
    }
    for (int off = 32; off; off >>= 1) {
        bu = max(bu, __shfl_xor(bu, off));
        bi = max(bi, __shfl_xor(bi, off));
    }
    if (lane == 0) { prevu[t] = bu; previ[t] = bi; }
}

// ---------------------------------------------------------------------------
// Kernel 2 (single block): connected components over prev edges (min-label
// propagation), partition into level-0 (no preds) vs tail, sort tail by
// (component, t), emit component start offsets.
// ---------------------------------------------------------------------------
__global__ __launch_bounds__(1024) void setup_kernel(
    const int* __restrict__ prevu, const int* __restrict__ previ,
    int* __restrict__ l0order, int* __restrict__ tailOrder,
    int* __restrict__ compStart, Hdr* __restrict__ hdr, int nev)
{
    __shared__ int lab[MAXEV];
    __shared__ int tmpT[MAXEV];
    __shared__ int skey[MAXEV];
    __shared__ int schanged, sntail, snl0;

    int tid = threadIdx.x;
    for (int t = tid; t < nev; t += 1024) lab[t] = t;
    if (tid == 0) { sntail = 0; snl0 = 0; }
    __syncthreads();

    for (int it = 0; it < nev; ++it) {
        if (tid == 0) schanged = 0;
        __syncthreads();
        for (int t = tid; t < nev; t += 1024) {
            int m = lab[t];
            int pu = prevu[t], pi = previ[t];
            if (pu >= 0) m = min(m, lab[pu]);
            if (pi >= 0) m = min(m, lab[pi]);
            if (m < lab[t]) { atomicMin(&lab[t], m); schanged = 1; }
            if (pu >= 0 && m < lab[pu]) { atomicMin(&lab[pu], m); schanged = 1; }
            if (pi >= 0 && m < lab[pi]) { atomicMin(&lab[pi], m); schanged = 1; }
        }
        __syncthreads();
        if (!schanged) break;
        __syncthreads();
    }

    for (int t = tid; t < nev; t += 1024) {
        if (prevu[t] >= 0 || previ[t] >= 0) tmpT[atomicAdd(&sntail, 1)] = t;
        else                                 l0order[atomicAdd(&snl0, 1)] = t;
    }
    __syncthreads();
    int ntail = sntail;

    for (int i = tid; i < ntail; i += 1024)
        skey[i] = (lab[tmpT[i]] << 12) | tmpT[i];
    __syncthreads();

    for (int i = tid; i < ntail; i += 1024) {   // rank sort (unique keys)
        int k = skey[i], r = 0;
        for (int j = 0; j < ntail; ++j) r += (skey[j] < k);
        tailOrder[r] = tmpT[i];
        lab[r] = k;                              // sorted keys
    }
    __syncthreads();

    if (tid == 0) {
        int nc = 0;
        for (int i = 0; i < ntail; ++i)
            if (i == 0 || (lab[i] >> 12) != (lab[i - 1] >> 12))
                compStart[nc++] = i;
        compStart[nc] = ntail;
        hdr->ncomp = nc;
        hdr->nl0 = snl0;
    }
}

// ---------------------------------------------------------------------------
// Kernel 3a: gather level-0 inputs into dense Xu/Xv [NP64,128], zero-padded.
// ---------------------------------------------------------------------------
__global__ __launch_bounds__(256) void gather_kernel(
    const float* __restrict__ U0, const float* __restrict__ V0,
    const int* __restrict__ uids, const int* __restrict__ iids,
    const int* __restrict__ l0order, const Hdr* __restrict__ hdr,
    float* __restrict__ Xu, float* __restrict__ Xv)
{
    int nl0 = hdr->nl0;
    int NP64 = (nl0 + 63) & ~63;
    int sub = threadIdx.x >> 5;
    int lane = threadIdx.x & 31;
    int e = blockIdx.x * 8 + sub;
    if (e >= NP64) return;
    float4* xu = (float4*)(Xu + (size_t)e * EMB);
    float4* xv = (float4*)(Xv + (size_t)e * EMB);
    if (e < nl0) {
        int t = l0order[e];
        const float4* up = (const float4*)(U0 + (size_t)uids[t] * EMB);
        const float4* vp = (const float4*)(V0 + (size_t)iids[t] * EMB);
        xu[lane] = up[lane];
        xv[lane] = vp[lane];
    } else {
        float4 zz = make_float4(0.f, 0.f, 0.f, 0.f);
        xu[lane] = zz;
        xv[lane] = zz;
    }
}

// ---------------------------------------------------------------------------
// Kernel 3b: gate GEMM. G_u = Xu @ [Wuh;Wii]^T, G_v = Xv @ [Wui;Wih]^T.
// 64x64 tile, K=128 in two halves, XOR-swizzled LDS, 4x4 register tile.
// ---------------------------------------------------------------------------
__global__ __launch_bounds__(256, 4) void gate_gemm_kernel(
    const float* __restrict__ Xu, const float* __restrict__ Xv,
    const float* __restrict__ Wuh, const float* __restrict__ Wii,
    const float* __restrict__ Wui, const float* __restrict__ Wih,
    const Hdr* __restrict__ hdr,
    float* __restrict__ Gu, float* __restrict__ Gv)
{
    __shared__ float4 Xs[1024];
    __shared__ float4 Ws[1024];
    int nl0 = hdr->nl0;
    int NP64 = (nl0 + 63) & ~63;
    int ev0 = blockIdx.x * 64;
    if (ev0 >= NP64) return;
    int z = blockIdx.z;
    int j = blockIdx.y;
    const float* X  = z ? Xv : Xu;
    const float* W1 = z ? Wui : Wuh;
    const float* W2 = z ? Wih : Wii;
    float* G = z ? Gv : Gu;
    const float* Wsrc = (j < 6) ? W1 : W2;
    int row0 = ((j < 6) ? j : j - 6) * 64;

    int tid = threadIdx.x;
    int e0 = (tid >> 4) * 4, r0 = (tid & 15) * 4;
    int sx = (e0 >> 2) & 7, sw = (r0 >> 2) & 7;
    float acc[4][4] = {};
    const float4* X4 = (const float4*)X;
    const float4* W4 = (const float4*)Wsrc;

    for (int kh = 0; kh < 2; ++kh) {
        __syncthreads();
        #pragma unroll
        for (int p = 0; p < 4; ++p) {
            int q = p * 256 + tid;
            int r = q >> 4, c4 = q & 15;
            int sr = (r >> 2) & 7;
            Xs[r * 16 + (c4 ^ sr)] = X4[(size_t)(ev0 + r) * 32 + kh * 16 + c4];
            Ws[r * 16 + (c4 ^ sr)] = W4[(size_t)(row0 + r) * 32 + kh * 16 + c4];
        }
        __syncthreads();
        #pragma unroll 4
        for (int k4 = 0; k4 < 16; ++k4) {
            float4 xa[4], wb[4];
            #pragma unroll
            for (int i = 0; i < 4; ++i) xa[i] = Xs[(e0 + i) * 16 + (k4 ^ sx)];
            #pragma unroll
            for (int jj = 0; jj < 4; ++jj) wb[jj] = Ws[(r0 + jj) * 16 + (k4 ^ sw)];
            #pragma unroll
            for (int i = 0; i < 4; ++i) {
                #pragma unroll
                for (int jj = 0; jj < 4; ++jj) {
                    acc[i][jj] = fmaf(xa[i].x, wb[jj].x, acc[i][jj]);
                    acc[i][jj] = fmaf(xa[i].y, wb[jj].y, acc[i][jj]);
                    acc[i][jj] = fmaf(xa[i].z, wb[jj].z, acc[i][jj]);
                    acc[i][jj] = fmaf(xa[i].w, wb[jj].w, acc[i][jj]);
                }
            }
        }
    }
    int col0 = j * 64 + r0;
    #pragma unroll
    for (int i = 0; i < 4; ++i) {
        float4 v = make_float4(acc[i][0], acc[i][1], acc[i][2], acc[i][3]);
        *(float4*)&G[(size_t)(ev0 + e0 + i) * 768 + col0] = v;
    }
}

// ---------------------------------------------------------------------------
// Kernel 3c: gate combine -> NU/NV for level-0 events.
// ---------------------------------------------------------------------------
__global__ __launch_bounds__(256) void combine_kernel(
    const float* __restrict__ Gu, const float* __restrict__ Gv,
    const float* __restrict__ Xu, const float* __restrict__ Xv,
    const float* __restrict__ bui, const float* __restrict__ buh,
    const float* __restrict__ bii, const float* __restrict__ bih,
    const int* __restrict__ l0order, const Hdr* __restrict__ hdr,
    float* __restrict__ NU, float* __restrict__ NV)
{
    int nl0 = hdr->nl0;
    int e = blockIdx.x * 2 + (threadIdx.x >> 7);
    int rr = threadIdx.x & 127;
    if (e >= nl0) return;
    int t = l0order[e];
    const float* gu = Gu + (size_t)e * 768;
    const float* gv = Gv + (size_t)e * 768;
    float r = sigmoidf_(gv[rr] + bui[rr] + gu[rr] + buh[rr]);
    float zg = sigmoidf_(gv[128 + rr] + bui[128 + rr] + gu[128 + rr] + buh[128 + rr]);
    float n = tanhf(gv[256 + rr] + bui[256 + rr] + r * (gu[256 + rr] + buh[256 + rr]));
    float u = Xu[(size_t)e * EMB + rr];
    NU[(size_t)t * EMB + rr] = (1.f - zg) * n + zg * u;
    float r2 = sigmoidf_(gu[384 + rr] + bii[rr] + gv[384 + rr] + bih[rr]);
    float z2 = sigmoidf_(gu[512 + rr] + bii[128 + rr] + gv[512 + rr] + bih[128 + rr]);
    float n2 = tanhf(gu[640 + rr] + bii[256 + rr] + r2 * (gv[640 + rr] + bih[256 + rr]));
    float v = Xv[(size_t)e * EMB + rr];
    NV[(size_t)t * EMB + rr] = (1.f - z2) * n2 + z2 * v;
}

// ---------------------------------------------------------------------------
// Kernel 4: dependent events. One block per component, sequential in t within
// the component (all deps component-internal; same block -> same CU -> L1
// coherent, no fences/flags needed). Inner loop: 16-lane groups x 8-row
// batches -> 16 loads in flight per lane, 12 serial L2 batches per event.
// ---------------------------------------------------------------------------
__global__ __launch_bounds__(256) void tail_kernel(
    const float* __restrict__ U0,  const float* __restrict__ V0,
    const float* __restrict__ Wui, const float* __restrict__ Wuh,
    const float* __restrict__ bui, const float* __restrict__ buh,
    const float* __restrict__ Wii, const float* __restrict__ Wih,
    const float* __restrict__ bii, const float* __restrict__ bih,
    const int* __restrict__ uids,  const int* __restrict__ iids,
    const int* __restrict__ prevu, const int* __restrict__ previ,
    const int* __restrict__ tailOrder, const int* __restrict__ compStart,
    const Hdr* __restrict__ hdr,
    float* __restrict__ NU, float* __restrict__ NV)
{
    __shared__ __align__(16) float su[EMB];
    __shared__ __align__(16) float sv[EMB];
    __shared__ float gg[1536];
    int tid = threadIdx.x;
    int ncomp = hdr->ncomp;

    for (int c = blockIdx.x; c < ncomp; c += gridDim.x) {
        int kb = compStart[c], ke = compStart[c + 1];
        for (int k = kb; k < ke; ++k) {
            int t = tailOrder[k];
            int pu = prevu[t], pi = previ[t];
            const float* up = (pu < 0) ? U0 + (size_t)uids[t] * EMB : NU + (size_t)pu * EMB;
            const float* vp = (pi < 0) ? V0 + (size_t)iids[t] * EMB : NV + (size_t)pi * EMB;
            __syncthreads();   // protect su/sv/gg reuse across events
            if (tid < EMB) su[tid] = up[tid];
            else           sv[tid - EMB] = vp[tid - EMB];
            __syncthreads();

            int g = tid >> 4, j = tid & 15;
            #pragma unroll
            for (int mat = 0; mat < 4; ++mat) {
                const float* W = (mat == 0) ? Wui : (mat == 1) ? Wuh : (mat == 2) ? Wii : Wih;
                const float* x = (mat == 1 || mat == 2) ? su : sv;
                const float4* x4 = (const float4*)x;
                float4 xa = x4[2 * j], xb = x4[2 * j + 1];
                #pragma unroll
                for (int b = 0; b < 3; ++b) {
                    int rbase = g * 24 + b * 8;            // 0..383 within mat
                    float4 w0[8], w1[8];
                    #pragma unroll
                    for (int q = 0; q < 8; ++q) {
                        const float4* W4 = (const float4*)(W + (size_t)(rbase + q) * EMB);
                        w0[q] = W4[2 * j]; w1[q] = W4[2 * j + 1];
                    }
                    #pragma unroll
                    for (int q = 0; q < 8; ++q) {
                        float s = w0[q].x * xa.x + w0[q].y * xa.y
                                + w0[q].z * xa.z + w0[q].w * xa.w
                                + w1[q].x * xb.x + w1[q].y * xb.y
                                + w1[q].z * xb.z + w1[q].w * xb.w;
                        s += __shfl_xor(s, 1); s += __shfl_xor(s, 2);
                        s += __shfl_xor(s, 4); s += __shfl_xor(s, 8);
                        if (j == q) gg[mat * 384 + rbase + q] = s;
                    }
                }
            }
            __syncthreads();

            if (tid < EMB) {
                int e = tid;
                float r_ = sigmoidf_(gg[e] + bui[e] + gg[384 + e] + buh[e]);
                float z_ = sigmoidf_(gg[128 + e] + bui[128 + e] + gg[512 + e] + buh[128 + e]);
                float n_ = tanhf(gg[256 + e] + bui[256 + e] + r_ * (gg[640 + e] + buh[256 + e]));
                NU[(size_t)t * EMB + e] = (1.f - z_) * n_ + z_ * su[e];
            } else {
                int e = tid - EMB;
                float r_ = sigmoidf_(gg[768 + e] + bii[e] + gg[1152 + e] + bih[e]);
                float z_ = sigmoidf_(gg[896 + e] + bii[128 + e] + gg[1280 + e] + bih[128 + e]);
                float n_ = tanhf(gg[1024 + e] + bii[256 + e] + r_ * (gg[1408 + e] + bih[256 + e]));
                NV[(size_t)t * EMB + e] = (1.f - z_) * n_ + z_ * sv[e];
            }
        }
    }
}

// ---------------------------------------------------------------------------
// Kernel 5a: gather INPUT u,v for ALL events into XAu/XAv + loss output.
// ---------------------------------------------------------------------------
__global__ __launch_bounds__(256) void gatherall_kernel(
    const float* __restrict__ U0, const float* __restrict__ V0,
    const int* __restrict__ uids, const int* __restrict__ iids,
    const int* __restrict__ prevu, const int* __restrict__ previ,
    const float* __restrict__ NU, const float* __restrict__ NV,
    float* __restrict__ XAu, float* __restrict__ XAv,
    float* __restrict__ out, int nev)
{
    int sub = threadIdx.x >> 5;
    int lane = threadIdx.x & 31;
    int t = blockIdx.x * 8 + sub;
    if (t >= nev) return;
    int pu = prevu[t], pi = previ[t];
    const float4* up = (const float4*)(pu < 0 ?
        U0 + (size_t)uids[t] * EMB : NU + (size_t)pu * EMB);
    const float4* vp = (const float4*)(pi < 0 ?
        V0 + (size_t)iids[t] * EMB : NV + (size_t)pi * EMB);
    float4 a = up[lane], c = vp[lane];
    ((float4*)(XAu + (size_t)t * EMB))[lane] = a;
    ((float4*)(XAv + (size_t)t * EMB))[lane] = c;
    float dp = a.x * c.x + a.y * c.y + a.z * c.z + a.w * c.w;
    dp += __shfl_xor(dp, 1); dp += __shfl_xor(dp, 2);
    dp += __shfl_xor(dp, 4); dp += __shfl_xor(dp, 8);
    dp += __shfl_xor(dp, 16);
    if (lane == 0) out[2 * (size_t)t] = -logf(softplusf_(dp) + 1e-10f);
}

// ---------------------------------------------------------------------------
// Kernel 5b: T1 GEMM. H1 = relu([XAu|XAv] @ T1w^T + b). K=256 in 4 chunks.
// ---------------------------------------------------------------------------
__global__ __launch_bounds__(256, 4) void t1_gemm_kernel(
    const float* __restrict__ XAu, const float* __restrict__ XAv,
    const float* __restrict__ T1w, const float* __restrict__ T1b,
    float* __restrict__ H1, int nev)
{
    __shared__ float4 Xs[1024];
    __shared__ float4 Ws[1024];
    int ev0 = blockIdx.x * 64;
    int row0 = blockIdx.y * 64;
    int tid = threadIdx.x;
    int e0 = (tid >> 4) * 4, r0 = (tid & 15) * 4;
    int sx = (e0 >> 2) & 7, sw = (r0 >> 2) & 7;
    float acc[4][4] = {};
    const float4* W4 = (const float4*)T1w;

    for (int kh = 0; kh < 4; ++kh) {
        const float4* X4 = (const float4*)((kh < 2) ? XAu : XAv);
        int khh = kh & 1;
        __syncthreads();
        #pragma unroll
        for (int p = 0; p < 4; ++p) {
            int q = p * 256 + tid;
            int r = q >> 4, c4 = q & 15;
            int sr = (r >> 2) & 7;
            Xs[r * 16 + (c4 ^ sr)] = X4[(size_t)(ev0 + r) * 32 + khh * 16 + c4];
            Ws[r * 16 + (c4 ^ sr)] = W4[(size_t)(row0 + r) * 64 + kh * 16 + c4];
        }
        __syncthreads();
        #pragma unroll 4
        for (int k4 = 0; k4 < 16; ++k4) {
            float4 xa[4], wb[4];
            #pragma unroll
            for (int i = 0; i < 4; ++i) xa[i] = Xs[(e0 + i) * 16 + (k4 ^ sx)];
            #pragma unroll
            for (int jj = 0; jj < 4; ++jj) wb[jj] = Ws[(r0 + jj) * 16 + (k4 ^ sw)];
            #pragma unroll
            for (int i = 0; i < 4; ++i) {
                #pragma unroll
                for (int jj = 0; jj < 4; ++jj) {
                    acc[i][jj] = fmaf(xa[i].x, wb[jj].x, acc[i][jj]);
                    acc[i][jj] = fmaf(xa[i].y, wb[jj].y, acc[i][jj]);
                    acc[i][jj] = fmaf(xa[i].z, wb[jj].z, acc[i][jj]);
                    acc[i][jj] = fmaf(xa[i].w, wb[jj].w, acc[i][jj]);
                }
            }
        }
    }
    int col0 = row0 + r0;
    float b0 = T1b[col0], b1 = T1b[col0 + 1], b2 = T1b[col0 + 2], b3 = T1b[col0 + 3];
    #pragma unroll
    for (int i = 0; i < 4; ++i) {
        float4 v;
        v.x = fmaxf(acc[i][0] + b0, 0.f);
        v.y = fmaxf(acc[i][1] + b1, 0.f);
        v.z = fmaxf(acc[i][2] + b2, 0.f);
        v.w = fmaxf(acc[i][3] + b3, 0.f);
        *(float4*)&H1[(size_t)(ev0 + e0 + i) * EMB + col0] = v;
    }
}

// ---------------------------------------------------------------------------
// Kernel 5c: T2 + T3 + sigmoid. 16 events per block; T2w staged in LDS.
// ---------------------------------------------------------------------------
__global__ __launch_bounds__(256) void t2t3_kernel(
    const float* __restrict__ H1,
    const float* __restrict__ T2w, const float* __restrict__ T2b,
    const float* __restrict__ T3w, const float* __restrict__ T3b,
    float* __restrict__ out, int nev)
{
    __shared__ __align__(16) float w2s[32][132];
    __shared__ __align__(16) float h1s[16][132];
    __shared__ float h2s[16][36];
    int tid = threadIdx.x;
    int ev = tid >> 4, j = tid & 15;
    int t = blockIdx.x * 16 + ev;

    {
        const float4* s2 = (const float4*)T2w;
        #pragma unroll
        for (int i = 0; i < 4; ++i) {
            int q = i * 256 + tid;
            int r = q >> 5, c4 = q & 31;
            *(float4*)&w2s[r][c4 * 4] = s2[q];
        }
    }
    {
        const float4* h4 = (const float4*)(H1 + (size_t)(blockIdx.x * 16 + ev) * EMB);
        *(float4*)&h1s[ev][8 * j]     = h4[2 * j];
        *(float4*)&h1s[ev][8 * j + 4] = h4[2 * j + 1];
    }
    __syncthreads();

    float acc0 = T2b[2 * j], acc1 = T2b[2 * j + 1];
    const float4* wr0 = (const float4*)&w2s[2 * j][0];
    const float4* wr1 = (const float4*)&w2s[2 * j + 1][0];
    const float4* xh = (const float4*)&h1s[ev][0];
    #pragma unroll
    for (int k = 0; k < 32; ++k) {
        float4 x = xh[k], a = wr0[k], b = wr1[k];
        acc0 = fmaf(a.x, x.x, acc0); acc0 = fmaf(a.y, x.y, acc0);
        acc0 = fmaf(a.z, x.z, acc0); acc0 = fmaf(a.w, x.w, acc0);
        acc1 = fmaf(b.x, x.x, acc1); acc1 = fmaf(b.y, x.y, acc1);
        acc1 = fmaf(b.z, x.z, acc1); acc1 = fmaf(b.w, x.w, acc1);
    }
    h2s[ev][2 * j]     = fmaxf(acc0, 0.f);
    h2s[ev][2 * j + 1] = fmaxf(acc1, 0.f);
    __syncthreads();

    float p = T3w[2 * j] * h2s[ev][2 * j] + T3w[2 * j + 1] * h2s[ev][2 * j + 1];
    p += __shfl_xor(p, 1); p += __shfl_xor(p, 2);
    p += __shfl_xor(p, 4); p += __shfl_xor(p, 8);
    if (j == 0 && t < nev)
        out[2 * (size_t)t + 1] = sigmoidf_(p + T3b[0]);
}

// ---------------------------------------------------------------------------
extern "C" void kernel_launch(void* const* d_in, const int* in_sizes, int n_in,
                              void* d_out, int out_size, void* d_ws, size_t ws_size,
                              hipStream_t stream)
{
    const float* U0  = (const float*)d_in[0];
    const float* V0  = (const float*)d_in[1];
    const float* Wui = (const float*)d_in[2];
    const float* Wuh = (const float*)d_in[3];
    const float* bui = (const float*)d_in[4];
    const float* buh = (const float*)d_in[5];
    const float* Wii = (const float*)d_in[6];
    const float* Wih = (const float*)d_in[7];
    const float* bii = (const float*)d_in[8];
    const float* bih = (const float*)d_in[9];
    const float* T1w = (const float*)d_in[10];
    const float* T1b = (const float*)d_in[11];
    const float* T2w = (const float*)d_in[12];
    const float* T2b = (const float*)d_in[13];
    const float* T3w = (const float*)d_in[14];
    const float* T3b = (const float*)d_in[15];
    const int* uids  = (const int*)d_in[16];
    const int* iids  = (const int*)d_in[17];
    int nev = in_sizes[16];

    char* ws = (char*)d_ws;
    int* base = (int*)ws;
    int* prevu     = base;                 // MAXEV
    int* previ     = base + MAXEV;         // MAXEV
    int* l0order   = base + 2 * MAXEV;     // MAXEV
    int* tailOrder = base + 3 * MAXEV;     // MAXEV
    int* compStart = base + 4 * MAXEV;     // MAXEV+2
    Hdr* hdr       = (Hdr*)(base + 5 * MAXEV + 4);
    float* NU = (float*)(ws + (128 << 10));            // 2 MB
    float* NV = NU + (size_t)MAXEV * EMB;              // 2 MB
    float* Xu = NV + (size_t)MAXEV * EMB;              // 2 MB (reused as XAu)
    float* Xv = Xu + (size_t)MAXEV * EMB;              // 2 MB (reused as XAv)
    float* Gu = Xv + (size_t)MAXEV * EMB;              // 12.6 MB (reused as H1)
    float* Gv = Gu + (size_t)MAXEV * 768;              // 12.6 MB
    float* out = (float*)d_out;

    prev_kernel<<<nev, 64, 0, stream>>>(uids, iids, prevu, previ, nev);
    setup_kernel<<<1, 1024, 0, stream>>>(prevu, previ, l0order, tailOrder,
                                         compStart, hdr, nev);

    gather_kernel<<<(MAXEV + 7) / 8, 256, 0, stream>>>(
        U0, V0, uids, iids, l0order, hdr, Xu, Xv);
    gate_gemm_kernel<<<dim3(MAXEV / 64, 12, 2), 256, 0, stream>>>(
        Xu, Xv, Wuh, Wii, Wui, Wih, hdr, Gu, Gv);
    combine_kernel<<<(MAXEV + 1) / 2, 256, 0, stream>>>(
        Gu, Gv, Xu, Xv, bui, buh, bii, bih, l0order, hdr, NU, NV);
    tail_kernel<<<512, 256, 0, stream>>>(
        U0, V0, Wui, Wuh, bui, buh, Wii, Wih, bii, bih,
        uids, iids, prevu, previ, tailOrder, compStart, hdr, NU, NV);

    float* XAu = Xu;   // Xu/Xv dead after combine
    float* XAv = Xv;
    float* H1  = Gu;   // Gu dead after combine
    gatherall_kernel<<<(nev + 7) / 8, 256, 0, stream>>>(
        U0, V0, uids, iids, prevu, previ, NU, NV, XAu, XAv, out, nev);
    t1_gemm_kernel<<<dim3((nev + 63) / 64, 2), 256, 0, stream>>>(
        XAu, XAv, T1w, T1b, H1, nev);
    t2t3_kernel<<<(nev + 15) / 16, 256, 0, stream>>>(
        H1, T2w, T2b, T3w, T3b, out, nev);
}

// Round 7
// 167.790 us; speedup vs baseline: 1.4718x; 1.4718x over previous
//
#include <hip/hip_runtime.h>
#include <math.h>

#define EMB 128
#define MAXEV 4096

struct Hdr { int nl0; int ncomp; };

__device__ __forceinline__ float sigmoidf_(float x) { return 1.0f / (1.0f + expf(-x)); }
__device__ __forceinline__ float softplusf_(float x) {
    return (x > 0.f) ? x + log1pf(expf(-x)) : log1pf(expf(x));
}

// ---------------------------------------------------------------------------
// Kernel 1: most recent earlier event with same user / item id.
// ---------------------------------------------------------------------------
__global__ __launch_bounds__(64) void prev_kernel(
    const int* __restrict__ uids, const int* __restrict__ iids,
    int* __restrict__ prevu, int* __restrict__ previ, int nev)
{
    int t = blockIdx.x;
    if (t >= nev) return;
    int lane = threadIdx.x;
    int myu = uids[t], myi = iids[t];
    int bu = -1, bi = -1;
    for (int j = lane; j < t; j += 64) {
        if (uids[j] == myu) bu = j;
        if (iids[j] == myi) bi = j;
    }
    for (int off = 32; off; off >>= 1) {
        bu = max(bu, __shfl_xor(bu, off));
        bi = max(bi, __shfl_xor(bi, off));
    }
    if (lane == 0) { prevu[t] = bu; previ[t] = bi; }
}

// ---------------------------------------------------------------------------
// Kernel 2 (single block): connected components over prev edges (min-label
// propagation), partition into level-0 (no preds) vs tail, sort tail by
// (component, t), emit component start offsets.
// ---------------------------------------------------------------------------
__global__ __launch_bounds__(1024) void setup_kernel(
    const int* __restrict__ prevu, const int* __restrict__ previ,
    int* __restrict__ l0order, int* __restrict__ tailOrder,
    int* __restrict__ compStart, Hdr* __restrict__ hdr, int nev)
{
    __shared__ int lab[MAXEV];
    __shared__ int tmpT[MAXEV];
    __shared__ int skey[MAXEV];
    __shared__ int schanged, sntail, snl0;

    int tid = threadIdx.x;
    for (int t = tid; t < nev; t += 1024) lab[t] = t;
    if (tid == 0) { sntail = 0; snl0 = 0; }
    __syncthreads();

    for (int it = 0; it < nev; ++it) {
        if (tid == 0) schanged = 0;
        __syncthreads();
        for (int t = tid; t < nev; t += 1024) {
            int m = lab[t];
            int pu = prevu[t], pi = previ[t];
            if (pu >= 0) m = min(m, lab[pu]);
            if (pi >= 0) m = min(m, lab[pi]);
            if (m < lab[t]) { atomicMin(&lab[t], m); schanged = 1; }
            if (pu >= 0 && m < lab[pu]) { atomicMin(&lab[pu], m); schanged = 1; }
            if (pi >= 0 && m < lab[pi]) { atomicMin(&lab[pi], m); schanged = 1; }
        }
        __syncthreads();
        if (!schanged) break;
        __syncthreads();
    }

    for (int t = tid; t < nev; t += 1024) {
        if (prevu[t] >= 0 || previ[t] >= 0) tmpT[atomicAdd(&sntail, 1)] = t;
        else                                 l0order[atomicAdd(&snl0, 1)] = t;
    }
    __syncthreads();
    int ntail = sntail;

    for (int i = tid; i < ntail; i += 1024)
        skey[i] = (lab[tmpT[i]] << 12) | tmpT[i];
    __syncthreads();

    for (int i = tid; i < ntail; i += 1024) {   // rank sort (unique keys)
        int k = skey[i], r = 0;
        for (int j = 0; j < ntail; ++j) r += (skey[j] < k);
        tailOrder[r] = tmpT[i];
        lab[r] = k;                              // sorted keys
    }
    __syncthreads();

    if (tid == 0) {
        int nc = 0;
        for (int i = 0; i < ntail; ++i)
            if (i == 0 || (lab[i] >> 12) != (lab[i - 1] >> 12))
                compStart[nc++] = i;
        compStart[nc] = ntail;
        hdr->ncomp = nc;
        hdr->nl0 = snl0;
    }
}

// ---------------------------------------------------------------------------
// Kernel 3a: gather level-0 inputs into dense Xu/Xv [NP64,128], zero-padded.
// ---------------------------------------------------------------------------
__global__ __launch_bounds__(256) void gather_kernel(
    const float* __restrict__ U0, const float* __restrict__ V0,
    const int* __restrict__ uids, const int* __restrict__ iids,
    const int* __restrict__ l0order, const Hdr* __restrict__ hdr,
    float* __restrict__ Xu, float* __restrict__ Xv)
{
    int nl0 = hdr->nl0;
    int NP64 = (nl0 + 63) & ~63;
    int sub = threadIdx.x >> 5;
    int lane = threadIdx.x & 31;
    int e = blockIdx.x * 8 + sub;
    if (e >= NP64) return;
    float4* xu = (float4*)(Xu + (size_t)e * EMB);
    float4* xv = (float4*)(Xv + (size_t)e * EMB);
    if (e < nl0) {
        int t = l0order[e];
        const float4* up = (const float4*)(U0 + (size_t)uids[t] * EMB);
        const float4* vp = (const float4*)(V0 + (size_t)iids[t] * EMB);
        xu[lane] = up[lane];
        xv[lane] = vp[lane];
    } else {
        float4 zz = make_float4(0.f, 0.f, 0.f, 0.f);
        xu[lane] = zz;
        xv[lane] = zz;
    }
}

// ---------------------------------------------------------------------------
// Kernel 3b: gate GEMM. G_u = Xu @ [Wuh;Wii]^T, G_v = Xv @ [Wui;Wih]^T.
// 64x64 tile, K=128 in two halves, XOR-swizzled LDS, 4x4 register tile.
// ---------------------------------------------------------------------------
__global__ __launch_bounds__(256, 4) void gate_gemm_kernel(
    const float* __restrict__ Xu, const float* __restrict__ Xv,
    const float* __restrict__ Wuh, const float* __restrict__ Wii,
    const float* __restrict__ Wui, const float* __restrict__ Wih,
    const Hdr* __restrict__ hdr,
    float* __restrict__ Gu, float* __restrict__ Gv)
{
    __shared__ float4 Xs[1024];
    __shared__ float4 Ws[1024];
    int nl0 = hdr->nl0;
    int NP64 = (nl0 + 63) & ~63;
    int ev0 = blockIdx.x * 64;
    if (ev0 >= NP64) return;
    int z = blockIdx.z;
    int j = blockIdx.y;
    const float* X  = z ? Xv : Xu;
    const float* W1 = z ? Wui : Wuh;
    const float* W2 = z ? Wih : Wii;
    float* G = z ? Gv : Gu;
    const float* Wsrc = (j < 6) ? W1 : W2;
    int row0 = ((j < 6) ? j : j - 6) * 64;

    int tid = threadIdx.x;
    int e0 = (tid >> 4) * 4, r0 = (tid & 15) * 4;
    int sx = (e0 >> 2) & 7, sw = (r0 >> 2) & 7;
    float acc[4][4] = {};
    const float4* X4 = (const float4*)X;
    const float4* W4 = (const float4*)Wsrc;

    for (int kh = 0; kh < 2; ++kh) {
        __syncthreads();
        #pragma unroll
        for (int p = 0; p < 4; ++p) {
            int q = p * 256 + tid;
            int r = q >> 4, c4 = q & 15;
            int sr = (r >> 2) & 7;
            Xs[r * 16 + (c4 ^ sr)] = X4[(size_t)(ev0 + r) * 32 + kh * 16 + c4];
            Ws[r * 16 + (c4 ^ sr)] = W4[(size_t)(row0 + r) * 32 + kh * 16 + c4];
        }
        __syncthreads();
        #pragma unroll 4
        for (int k4 = 0; k4 < 16; ++k4) {
            float4 xa[4], wb[4];
            #pragma unroll
            for (int i = 0; i < 4; ++i) xa[i] = Xs[(e0 + i) * 16 + (k4 ^ sx)];
            #pragma unroll
            for (int jj = 0; jj < 4; ++jj) wb[jj] = Ws[(r0 + jj) * 16 + (k4 ^ sw)];
            #pragma unroll
            for (int i = 0; i < 4; ++i) {
                #pragma unroll
                for (int jj = 0; jj < 4; ++jj) {
                    acc[i][jj] = fmaf(xa[i].x, wb[jj].x, acc[i][jj]);
                    acc[i][jj] = fmaf(xa[i].y, wb[jj].y, acc[i][jj]);
                    acc[i][jj] = fmaf(xa[i].z, wb[jj].z, acc[i][jj]);
                    acc[i][jj] = fmaf(xa[i].w, wb[jj].w, acc[i][jj]);
                }
            }
        }
    }
    int col0 = j * 64 + r0;
    #pragma unroll
    for (int i = 0; i < 4; ++i) {
        float4 v = make_float4(acc[i][0], acc[i][1], acc[i][2], acc[i][3]);
        *(float4*)&G[(size_t)(ev0 + e0 + i) * 768 + col0] = v;
    }
}

// ---------------------------------------------------------------------------
// Kernel 3c: gate combine -> NU/NV for level-0 events.
// ---------------------------------------------------------------------------
__global__ __launch_bounds__(256) void combine_kernel(
    const float* __restrict__ Gu, const float* __restrict__ Gv,
    const float* __restrict__ Xu, const float* __restrict__ Xv,
    const float* __restrict__ bui, const float* __restrict__ buh,
    const float* __restrict__ bii, const float* __restrict__ bih,
    const int* __restrict__ l0order, const Hdr* __restrict__ hdr,
    float* __restrict__ NU, float* __restrict__ NV)
{
    int nl0 = hdr->nl0;
    int e = blockIdx.x * 2 + (threadIdx.x >> 7);
    int rr = threadIdx.x & 127;
    if (e >= nl0) return;
    int t = l0order[e];
    const float* gu = Gu + (size_t)e * 768;
    const float* gv = Gv + (size_t)e * 768;
    float r = sigmoidf_(gv[rr] + bui[rr] + gu[rr] + buh[rr]);
    float zg = sigmoidf_(gv[128 + rr] + bui[128 + rr] + gu[128 + rr] + buh[128 + rr]);
    float n = tanhf(gv[256 + rr] + bui[256 + rr] + r * (gu[256 + rr] + buh[256 + rr]));
    float u = Xu[(size_t)e * EMB + rr];
    NU[(size_t)t * EMB + rr] = (1.f - zg) * n + zg * u;
    float r2 = sigmoidf_(gu[384 + rr] + bii[rr] + gv[384 + rr] + bih[rr]);
    float z2 = sigmoidf_(gu[512 + rr] + bii[128 + rr] + gv[512 + rr] + bih[128 + rr]);
    float n2 = tanhf(gu[640 + rr] + bii[256 + rr] + r2 * (gv[640 + rr] + bih[256 + rr]));
    float v = Xv[(size_t)e * EMB + rr];
    NV[(size_t)t * EMB + rr] = (1.f - z2) * n2 + z2 * v;
}

// ---------------------------------------------------------------------------
// Kernel 4: dependent events. One block per component, sequential in t within
// the component. Inner loop: 16-lane groups x 8-row batches (16 loads in
// flight). #pragma unroll 1 on mat/b loops is LOAD-BEARING: full unroll
// hoists 12x16 float4 weight loads -> ~768 live regs -> scratch spill
// (round 5/6: VGPR=256, 78-106 MB WRITE_SIZE, kernel 100% spill-BW-bound).
// ---------------------------------------------------------------------------
__global__ __launch_bounds__(256) void tail_kernel(
    const float* __restrict__ U0,  const float* __restrict__ V0,
    const float* __restrict__ Wui, const float* __restrict__ Wuh,
    const float* __restrict__ bui, const float* __restrict__ buh,
    const float* __restrict__ Wii, const float* __restrict__ Wih,
    const float* __restrict__ bii, const float* __restrict__ bih,
    const int* __restrict__ uids,  const int* __restrict__ iids,
    const int* __restrict__ prevu, const int* __restrict__ previ,
    const int* __restrict__ tailOrder, const int* __restrict__ compStart,
    const Hdr* __restrict__ hdr,
    float* __restrict__ NU, float* __restrict__ NV)
{
    __shared__ __align__(16) float su[EMB];
    __shared__ __align__(16) float sv[EMB];
    __shared__ float gg[1536];
    int tid = threadIdx.x;
    int ncomp = hdr->ncomp;

    for (int c = blockIdx.x; c < ncomp; c += gridDim.x) {
        int kb = compStart[c], ke = compStart[c + 1];
        for (int k = kb; k < ke; ++k) {
            int t = tailOrder[k];
            int pu = prevu[t], pi = previ[t];
            const float* up = (pu < 0) ? U0 + (size_t)uids[t] * EMB : NU + (size_t)pu * EMB;
            const float* vp = (pi < 0) ? V0 + (size_t)iids[t] * EMB : NV + (size_t)pi * EMB;
            __syncthreads();   // protect su/sv/gg reuse across events
            if (tid < EMB) su[tid] = up[tid];
            else           sv[tid - EMB] = vp[tid - EMB];
            __syncthreads();

            int g = tid >> 4, j = tid & 15;
            #pragma unroll 1
            for (int mat = 0; mat < 4; ++mat) {
                const float* W = (mat == 0) ? Wui : (mat == 1) ? Wuh : (mat == 2) ? Wii : Wih;
                const float* x = (mat == 1 || mat == 2) ? su : sv;
                const float4* x4 = (const float4*)x;
                float4 xa = x4[2 * j], xb = x4[2 * j + 1];
                #pragma unroll 1
                for (int b = 0; b < 3; ++b) {
                    int rbase = g * 24 + b * 8;            // 0..383 within mat
                    float4 w0[8], w1[8];
                    #pragma unroll
                    for (int q = 0; q < 8; ++q) {
                        const float4* W4 = (const float4*)(W + (size_t)(rbase + q) * EMB);
                        w0[q] = W4[2 * j]; w1[q] = W4[2 * j + 1];
                    }
                    #pragma unroll
                    for (int q = 0; q < 8; ++q) {
                        float s = w0[q].x * xa.x + w0[q].y * xa.y
                                + w0[q].z * xa.z + w0[q].w * xa.w
                                + w1[q].x * xb.x + w1[q].y * xb.y
                                + w1[q].z * xb.z + w1[q].w * xb.w;
                        s += __shfl_xor(s, 1); s += __shfl_xor(s, 2);
                        s += __shfl_xor(s, 4); s += __shfl_xor(s, 8);
                        if (j == q) gg[mat * 384 + rbase + q] = s;
                    }
                }
            }
            __syncthreads();

            if (tid < EMB) {
                int e = tid;
                float r_ = sigmoidf_(gg[e] + bui[e] + gg[384 + e] + buh[e]);
                float z_ = sigmoidf_(gg[128 + e] + bui[128 + e] + gg[512 + e] + buh[128 + e]);
                float n_ = tanhf(gg[256 + e] + bui[256 + e] + r_ * (gg[640 + e] + buh[256 + e]));
                NU[(size_t)t * EMB + e] = (1.f - z_) * n_ + z_ * su[e];
            } else {
                int e = tid - EMB;
                float r_ = sigmoidf_(gg[768 + e] + bii[e] + gg[1152 + e] + bih[e]);
                float z_ = sigmoidf_(gg[896 + e] + bii[128 + e] + gg[1280 + e] + bih[128 + e]);
                float n_ = tanhf(gg[1024 + e] + bii[256 + e] + r_ * (gg[1408 + e] + bih[256 + e]));
                NV[(size_t)t * EMB + e] = (1.f - z_) * n_ + z_ * sv[e];
            }
        }
    }
}

// ---------------------------------------------------------------------------
// Kernel 5a: gather INPUT u,v for ALL events into XAu/XAv + loss output.
// ---------------------------------------------------------------------------
__global__ __launch_bounds__(256) void gatherall_kernel(
    const float* __restrict__ U0, const float* __restrict__ V0,
    const int* __restrict__ uids, const int* __restrict__ iids,
    const int* __restrict__ prevu, const int* __restrict__ previ,
    const float* __restrict__ NU, const float* __restrict__ NV,
    float* __restrict__ XAu, float* __restrict__ XAv,
    float* __restrict__ out, int nev)
{
    int sub = threadIdx.x >> 5;
    int lane = threadIdx.x & 31;
    int t = blockIdx.x * 8 + sub;
    if (t >= nev) return;
    int pu = prevu[t], pi = previ[t];
    const float4* up = (const float4*)(pu < 0 ?
        U0 + (size_t)uids[t] * EMB : NU + (size_t)pu * EMB);
    const float4* vp = (const float4*)(pi < 0 ?
        V0 + (size_t)iids[t] * EMB : NV + (size_t)pi * EMB);
    float4 a = up[lane], c = vp[lane];
    ((float4*)(XAu + (size_t)t * EMB))[lane] = a;
    ((float4*)(XAv + (size_t)t * EMB))[lane] = c;
    float dp = a.x * c.x + a.y * c.y + a.z * c.z + a.w * c.w;
    dp += __shfl_xor(dp, 1); dp += __shfl_xor(dp, 2);
    dp += __shfl_xor(dp, 4); dp += __shfl_xor(dp, 8);
    dp += __shfl_xor(dp, 16);
    if (lane == 0) out[2 * (size_t)t] = -logf(softplusf_(dp) + 1e-10f);
}

// ---------------------------------------------------------------------------
// Kernel 5b: T1 GEMM. H1 = relu([XAu|XAv] @ T1w^T + b). K=256 in 4 chunks.
// ---------------------------------------------------------------------------
__global__ __launch_bounds__(256, 4) void t1_gemm_kernel(
    const float* __restrict__ XAu, const float* __restrict__ XAv,
    const float* __restrict__ T1w, const float* __restrict__ T1b,
    float* __restrict__ H1, int nev)
{
    __shared__ float4 Xs[1024];
    __shared__ float4 Ws[1024];
    int ev0 = blockIdx.x * 64;
    int row0 = blockIdx.y * 64;
    int tid = threadIdx.x;
    int e0 = (tid >> 4) * 4, r0 = (tid & 15) * 4;
    int sx = (e0 >> 2) & 7, sw = (r0 >> 2) & 7;
    float acc[4][4] = {};
    const float4* W4 = (const float4*)T1w;

    for (int kh = 0; kh < 4; ++kh) {
        const float4* X4 = (const float4*)((kh < 2) ? XAu : XAv);
        int khh = kh & 1;
        __syncthreads();
        #pragma unroll
        for (int p = 0; p < 4; ++p) {
            int q = p * 256 + tid;
            int r = q >> 4, c4 = q & 15;
            int sr = (r >> 2) & 7;
            Xs[r * 16 + (c4 ^ sr)] = X4[(size_t)(ev0 + r) * 32 + khh * 16 + c4];
            Ws[r * 16 + (c4 ^ sr)] = W4[(size_t)(row0 + r) * 64 + kh * 16 + c4];
        }
        __syncthreads();
        #pragma unroll 4
        for (int k4 = 0; k4 < 16; ++k4) {
            float4 xa[4], wb[4];
            #pragma unroll
            for (int i = 0; i < 4; ++i) xa[i] = Xs[(e0 + i) * 16 + (k4 ^ sx)];
            #pragma unroll
            for (int jj = 0; jj < 4; ++jj) wb[jj] = Ws[(r0 + jj) * 16 + (k4 ^ sw)];
            #pragma unroll
            for (int i = 0; i < 4; ++i) {
                #pragma unroll
                for (int jj = 0; jj < 4; ++jj) {
                    acc[i][jj] = fmaf(xa[i].x, wb[jj].x, acc[i][jj]);
                    acc[i][jj] = fmaf(xa[i].y, wb[jj].y, acc[i][jj]);
                    acc[i][jj] = fmaf(xa[i].z, wb[jj].z, acc[i][jj]);
                    acc[i][jj] = fmaf(xa[i].w, wb[jj].w, acc[i][jj]);
                }
            }
        }
    }
    int col0 = row0 + r0;
    float b0 = T1b[col0], b1 = T1b[col0 + 1], b2 = T1b[col0 + 2], b3 = T1b[col0 + 3];
    #pragma unroll
    for (int i = 0; i < 4; ++i) {
        float4 v;
        v.x = fmaxf(acc[i][0] + b0, 0.f);
        v.y = fmaxf(acc[i][1] + b1, 0.f);
        v.z = fmaxf(acc[i][2] + b2, 0.f);
        v.w = fmaxf(acc[i][3] + b3, 0.f);
        *(float4*)&H1[(size_t)(ev0 + e0 + i) * EMB + col0] = v;
    }
}

// ---------------------------------------------------------------------------
// Kernel 5c: T2 + T3 + sigmoid. 16 events per block; T2w staged in LDS.
// ---------------------------------------------------------------------------
__global__ __launch_bounds__(256) void t2t3_kernel(
    const float* __restrict__ H1,
    const float* __restrict__ T2w, const float* __restrict__ T2b,
    const float* __restrict__ T3w, const float* __restrict__ T3b,
    float* __restrict__ out, int nev)
{
    __shared__ __align__(16) float w2s[32][132];
    __shared__ __align__(16) float h1s[16][132];
    __shared__ float h2s[16][36];
    int tid = threadIdx.x;
    int ev = tid >> 4, j = tid & 15;
    int t = blockIdx.x * 16 + ev;

    {
        const float4* s2 = (const float4*)T2w;
        #pragma unroll
        for (int i = 0; i < 4; ++i) {
            int q = i * 256 + tid;
            int r = q >> 5, c4 = q & 31;
            *(float4*)&w2s[r][c4 * 4] = s2[q];
        }
    }
    {
        const float4* h4 = (const float4*)(H1 + (size_t)(blockIdx.x * 16 + ev) * EMB);
        *(float4*)&h1s[ev][8 * j]     = h4[2 * j];
        *(float4*)&h1s[ev][8 * j + 4] = h4[2 * j + 1];
    }
    __syncthreads();

    float acc0 = T2b[2 * j], acc1 = T2b[2 * j + 1];
    const float4* wr0 = (const float4*)&w2s[2 * j][0];
    const float4* wr1 = (const float4*)&w2s[2 * j + 1][0];
    const float4* xh = (const float4*)&h1s[ev][0];
    #pragma unroll
    for (int k = 0; k < 32; ++k) {
        float4 x = xh[k], a = wr0[k], b = wr1[k];
        acc0 = fmaf(a.x, x.x, acc0); acc0 = fmaf(a.y, x.y, acc0);
        acc0 = fmaf(a.z, x.z, acc0); acc0 = fmaf(a.w, x.w, acc0);
        acc1 = fmaf(b.x, x.x, acc1); acc1 = fmaf(b.y, x.y, acc1);
        acc1 = fmaf(b.z, x.z, acc1); acc1 = fmaf(b.w, x.w, acc1);
    }
    h2s[ev][2 * j]     = fmaxf(acc0, 0.f);
    h2s[ev][2 * j + 1] = fmaxf(acc1, 0.f);
    __syncthreads();

    float p = T3w[2 * j] * h2s[ev][2 * j] + T3w[2 * j + 1] * h2s[ev][2 * j + 1];
    p += __shfl_xor(p, 1); p += __shfl_xor(p, 2);
    p += __shfl_xor(p, 4); p += __shfl_xor(p, 8);
    if (j == 0 && t < nev)
        out[2 * (size_t)t + 1] = sigmoidf_(p + T3b[0]);
}

// ---------------------------------------------------------------------------
extern "C" void kernel_launch(void* const* d_in, const int* in_sizes, int n_in,
                              void* d_out, int out_size, void* d_ws, size_t ws_size,
                              hipStream_t stream)
{
    const float* U0  = (const float*)d_in[0];
    const float* V0  = (const float*)d_in[1];
    const float* Wui = (const float*)d_in[2];
    const float* Wuh = (const float*)d_in[3];
    const float* bui = (const float*)d_in[4];
    const float* buh = (const float*)d_in[5];
    const float* Wii = (const float*)d_in[6];
    const float* Wih = (const float*)d_in[7];
    const float* bii = (const float*)d_in[8];
    const float* bih = (const float*)d_in[9];
    const float* T1w = (const float*)d_in[10];
    const float* T1b = (const float*)d_in[11];
    const float* T2w = (const float*)d_in[12];
    const float* T2b = (const float*)d_in[13];
    const float* T3w = (const float*)d_in[14];
    const float* T3b = (const float*)d_in[15];
    const int* uids  = (const int*)d_in[16];
    const int* iids  = (const int*)d_in[17];
    int nev = in_sizes[16];

    char* ws = (char*)d_ws;
    int* base = (int*)ws;
    int* prevu     = base;                 // MAXEV
    int* previ     = base + MAXEV;         // MAXEV
    int* l0order   = base + 2 * MAXEV;     // MAXEV
    int* tailOrder = base + 3 * MAXEV;     // MAXEV
    int* compStart = base + 4 * MAXEV;     // MAXEV+2
    Hdr* hdr       = (Hdr*)(base + 5 * MAXEV + 4);
    float* NU = (float*)(ws + (128 << 10));            // 2 MB
    float* NV = NU + (size_t)MAXEV * EMB;              // 2 MB
    float* Xu = NV + (size_t)MAXEV * EMB;              // 2 MB (reused as XAu)
    float* Xv = Xu + (size_t)MAXEV * EMB;              // 2 MB (reused as XAv)
    float* Gu = Xv + (size_t)MAXEV * EMB;              // 12.6 MB (reused as H1)
    float* Gv = Gu + (size_t)MAXEV * 768;              // 12.6 MB
    float* out = (float*)d_out;

    prev_kernel<<<nev, 64, 0, stream>>>(uids, iids, prevu, previ, nev);
    setup_kernel<<<1, 1024, 0, stream>>>(prevu, previ, l0order, tailOrder,
                                         compStart, hdr, nev);

    gather_kernel<<<(MAXEV + 7) / 8, 256, 0, stream>>>(
        U0, V0, uids, iids, l0order, hdr, Xu, Xv);
    gate_gemm_kernel<<<dim3(MAXEV / 64, 12, 2), 256, 0, stream>>>(
        Xu, Xv, Wuh, Wii, Wui, Wih, hdr, Gu, Gv);
    combine_kernel<<<(MAXEV + 1) / 2, 256, 0, stream>>>(
        Gu, Gv, Xu, Xv, bui, buh, bii, bih, l0order, hdr, NU, NV);
    tail_kernel<<<512, 256, 0, stream>>>(
        U0, V0, Wui, Wuh, bui, buh, Wii, Wih, bii, bih,
        uids, iids, prevu, previ, tailOrder, compStart, hdr, NU, NV);

    float* XAu = Xu;   // Xu/Xv dead after combine
    float* XAv = Xv;
    float* H1  = Gu;   // Gu dead after combine
    gatherall_kernel<<<(nev + 7) / 8, 256, 0, stream>>>(
        U0, V0, uids, iids, prevu, previ, NU, NV, XAu, XAv, out, nev);
    t1_gemm_kernel<<<dim3((nev + 63) / 64, 2), 256, 0, stream>>>(
        XAu, XAv, T1w, T1b, H1, nev);
    t2t3_kernel<<<(nev + 15) / 16, 256, 0, stream>>>(
        H1, T2w, T2b, T3w, T3b, out, nev);
}

// Round 8
// 160.799 us; speedup vs baseline: 1.5358x; 1.0435x over previous
//
#include <hip/hip_runtime.h>
#include <math.h>

#define EMB 128
#define MAXEV 4096

struct Hdr { int nl0; int nl1; int ncomp2; };

__device__ __forceinline__ float sigmoidf_(float x) { return 1.0f / (1.0f + expf(-x)); }
__device__ __forceinline__ float softplusf_(float x) {
    return (x > 0.f) ? x + log1pf(expf(-x)) : log1pf(expf(x));
}

// ---------------------------------------------------------------------------
// Kernel 1: most recent earlier event with same user / item id.
// ---------------------------------------------------------------------------
__global__ __launch_bounds__(64) void prev_kernel(
    const int* __restrict__ uids, const int* __restrict__ iids,
    int* __restrict__ prevu, int* __restrict__ previ, int nev)
{
    int t = blockIdx.x;
    if (t >= nev) return;
    int lane = threadIdx.x;
    int myu = uids[t], myi = iids[t];
    int bu = -1, bi = -1;
    for (int j = lane; j < t; j += 64) {
        if (uids[j] == myu) bu = j;
        if (iids[j] == myi) bi = j;
    }
    for (int off = 32; off; off >>= 1) {
        bu = max(bu, __shfl_xor(bu, off));
        bi = max(bi, __shfl_xor(bi, off));
    }
    if (lane == 0) { prevu[t] = bu; previ[t] = bi; }
}

// ---------------------------------------------------------------------------
// Kernel 2 (single block): exact DAG levels (lev = 0 | 1+max(lev(preds))),
// partition into lev0 / lev1 / lev>=2; lev>=2 grouped by connected component
// (min-label over full graph, conservative) and sorted by (comp, t).
// ---------------------------------------------------------------------------
__global__ __launch_bounds__(1024) void setup_kernel(
    const int* __restrict__ prevu, const int* __restrict__ previ,
    int* __restrict__ order0, int* __restrict__ order1,
    int* __restrict__ tail2Order, int* __restrict__ compStart,
    Hdr* __restrict__ hdr, int nev)
{
    __shared__ int   lab[MAXEV];
    __shared__ int   tmpT[MAXEV];
    __shared__ int   skey[MAXEV];
    __shared__ short slev[MAXEV];
    __shared__ int   schanged, sn0, sn1, sn2;

    int tid = threadIdx.x;
    for (int t = tid; t < nev; t += 1024) { lab[t] = t; slev[t] = 0; }
    if (tid == 0) { sn0 = 0; sn1 = 0; sn2 = 0; }
    __syncthreads();

    // exact level relaxation (converges in DAG depth iterations)
    for (int it = 0; it < nev; ++it) {
        if (tid == 0) schanged = 0;
        __syncthreads();
        for (int t = tid; t < nev; t += 1024) {
            int pu = prevu[t], pi = previ[t];
            int nl = 0;
            if (pu >= 0) nl = slev[pu] + 1;
            if (pi >= 0) { int c = slev[pi] + 1; nl = nl > c ? nl : c; }
            if (nl > (int)slev[t]) { slev[t] = (short)nl; schanged = 1; }
        }
        __syncthreads();
        if (!schanged) break;
        __syncthreads();
    }

    // min-label components (for lev>=2 serialization only)
    for (int it = 0; it < nev; ++it) {
        if (tid == 0) schanged = 0;
        __syncthreads();
        for (int t = tid; t < nev; t += 1024) {
            int m = lab[t];
            int pu = prevu[t], pi = previ[t];
            if (pu >= 0) m = min(m, lab[pu]);
            if (pi >= 0) m = min(m, lab[pi]);
            if (m < lab[t]) { atomicMin(&lab[t], m); schanged = 1; }
            if (pu >= 0 && m < lab[pu]) { atomicMin(&lab[pu], m); schanged = 1; }
            if (pi >= 0 && m < lab[pi]) { atomicMin(&lab[pi], m); schanged = 1; }
        }
        __syncthreads();
        if (!schanged) break;
        __syncthreads();
    }

    for (int t = tid; t < nev; t += 1024) {
        int l = slev[t];
        if (l == 0)      order0[atomicAdd(&sn0, 1)] = t;
        else if (l == 1) order1[atomicAdd(&sn1, 1)] = t;
        else             tmpT[atomicAdd(&sn2, 1)] = t;
    }
    __syncthreads();
    int n2 = sn2;

    for (int i = tid; i < n2; i += 1024)
        skey[i] = (lab[tmpT[i]] << 12) | tmpT[i];
    __syncthreads();

    for (int i = tid; i < n2; i += 1024) {     // rank sort (unique keys)
        int k = skey[i], r = 0;
        for (int j = 0; j < n2; ++j) r += (skey[j] < k);
        tail2Order[r] = tmpT[i];
        lab[r] = k;                            // sorted keys
    }
    __syncthreads();

    if (tid == 0) {
        int nc = 0;
        for (int i = 0; i < n2; ++i)
            if (i == 0 || (lab[i] >> 12) != (lab[i - 1] >> 12))
                compStart[nc++] = i;
        compStart[nc] = n2;
        hdr->nl0 = sn0;
        hdr->nl1 = sn1;
        hdr->ncomp2 = nc;
    }
}

// ---------------------------------------------------------------------------
// Kernel 3a (both passes): gather event inputs (via prev indirection) into
// dense Xu/Xv [NP64,128], zero-padded to a multiple of 64 rows.
// ---------------------------------------------------------------------------
__global__ __launch_bounds__(256) void gatherx_kernel(
    const float* __restrict__ U0, const float* __restrict__ V0,
    const int* __restrict__ uids, const int* __restrict__ iids,
    const int* __restrict__ prevu, const int* __restrict__ previ,
    const float* __restrict__ NU, const float* __restrict__ NV,
    const int* __restrict__ order, const int* __restrict__ cnt_p,
    float* __restrict__ Xu, float* __restrict__ Xv)
{
    int cnt = *cnt_p;
    int NP64 = (cnt + 63) & ~63;
    int sub = threadIdx.x >> 5;
    int lane = threadIdx.x & 31;
    int e = blockIdx.x * 8 + sub;
    if (e >= NP64) return;
    float4* xu = (float4*)(Xu + (size_t)e * EMB);
    float4* xv = (float4*)(Xv + (size_t)e * EMB);
    if (e < cnt) {
        int t = order[e];
        int pu = prevu[t], pi = previ[t];
        const float4* up = (const float4*)(pu < 0 ?
            U0 + (size_t)uids[t] * EMB : NU + (size_t)pu * EMB);
        const float4* vp = (const float4*)(pi < 0 ?
            V0 + (size_t)iids[t] * EMB : NV + (size_t)pi * EMB);
        xu[lane] = up[lane];
        xv[lane] = vp[lane];
    } else {
        float4 zz = make_float4(0.f, 0.f, 0.f, 0.f);
        xu[lane] = zz;
        xv[lane] = zz;
    }
}

// ---------------------------------------------------------------------------
// Kernel 3b (both passes): gate GEMM. G_u = Xu @ [Wuh;Wii]^T,
// G_v = Xv @ [Wui;Wih]^T. 64x64 tile, K=128 in two halves, XOR-swizzled LDS,
// 4x4 register tile.
// ---------------------------------------------------------------------------
__global__ __launch_bounds__(256, 4) void gate_gemm_kernel(
    const float* __restrict__ Xu, const float* __restrict__ Xv,
    const float* __restrict__ Wuh, const float* __restrict__ Wii,
    const float* __restrict__ Wui, const float* __restrict__ Wih,
    const int* __restrict__ cnt_p,
    float* __restrict__ Gu, float* __restrict__ Gv)
{
    __shared__ float4 Xs[1024];
    __shared__ float4 Ws[1024];
    int cnt = *cnt_p;
    int NP64 = (cnt + 63) & ~63;
    int ev0 = blockIdx.x * 64;
    if (ev0 >= NP64) return;
    int z = blockIdx.z;
    int j = blockIdx.y;
    const float* X  = z ? Xv : Xu;
    const float* W1 = z ? Wui : Wuh;
    const float* W2 = z ? Wih : Wii;
    float* G = z ? Gv : Gu;
    const float* Wsrc = (j < 6) ? W1 : W2;
    int row0 = ((j < 6) ? j : j - 6) * 64;

    int tid = threadIdx.x;
    int e0 = (tid >> 4) * 4, r0 = (tid & 15) * 4;
    int sx = (e0 >> 2) & 7, sw = (r0 >> 2) & 7;
    float acc[4][4] = {};
    const float4* X4 = (const float4*)X;
    const float4* W4 = (const float4*)Wsrc;

    for (int kh = 0; kh < 2; ++kh) {
        __syncthreads();
        #pragma unroll
        for (int p = 0; p < 4; ++p) {
            int q = p * 256 + tid;
            int r = q >> 4, c4 = q & 15;
            int sr = (r >> 2) & 7;
            Xs[r * 16 + (c4 ^ sr)] = X4[(size_t)(ev0 + r) * 32 + kh * 16 + c4];
            Ws[r * 16 + (c4 ^ sr)] = W4[(size_t)(row0 + r) * 32 + kh * 16 + c4];
        }
        __syncthreads();
        #pragma unroll 4
        for (int k4 = 0; k4 < 16; ++k4) {
            float4 xa[4], wb[4];
            #pragma unroll
            for (int i = 0; i < 4; ++i) xa[i] = Xs[(e0 + i) * 16 + (k4 ^ sx)];
            #pragma unroll
            for (int jj = 0; jj < 4; ++jj) wb[jj] = Ws[(r0 + jj) * 16 + (k4 ^ sw)];
            #pragma unroll
            for (int i = 0; i < 4; ++i) {
                #pragma unroll
                for (int jj = 0; jj < 4; ++jj) {
                    acc[i][jj] = fmaf(xa[i].x, wb[jj].x, acc[i][jj]);
                    acc[i][jj] = fmaf(xa[i].y, wb[jj].y, acc[i][jj]);
                    acc[i][jj] = fmaf(xa[i].z, wb[jj].z, acc[i][jj]);
                    acc[i][jj] = fmaf(xa[i].w, wb[jj].w, acc[i][jj]);
                }
            }
        }
    }
    int col0 = j * 64 + r0;
    #pragma unroll
    for (int i = 0; i < 4; ++i) {
        float4 v = make_float4(acc[i][0], acc[i][1], acc[i][2], acc[i][3]);
        *(float4*)&G[(size_t)(ev0 + e0 + i) * 768 + col0] = v;
    }
}

// ---------------------------------------------------------------------------
// Kernel 3c (both passes): gate combine -> NU/NV.
// ---------------------------------------------------------------------------
__global__ __launch_bounds__(256) void combine_kernel(
    const float* __restrict__ Gu, const float* __restrict__ Gv,
    const float* __restrict__ Xu, const float* __restrict__ Xv,
    const float* __restrict__ bui, const float* __restrict__ buh,
    const float* __restrict__ bii, const float* __restrict__ bih,
    const int* __restrict__ order, const int* __restrict__ cnt_p,
    float* __restrict__ NU, float* __restrict__ NV)
{
    int cnt = *cnt_p;
    int e = blockIdx.x * 2 + (threadIdx.x >> 7);
    int rr = threadIdx.x & 127;
    if (e >= cnt) return;
    int t = order[e];
    const float* gu = Gu + (size_t)e * 768;
    const float* gv = Gv + (size_t)e * 768;
    float r = sigmoidf_(gv[rr] + bui[rr] + gu[rr] + buh[rr]);
    float zg = sigmoidf_(gv[128 + rr] + bui[128 + rr] + gu[128 + rr] + buh[128 + rr]);
    float n = tanhf(gv[256 + rr] + bui[256 + rr] + r * (gu[256 + rr] + buh[256 + rr]));
    float u = Xu[(size_t)e * EMB + rr];
    NU[(size_t)t * EMB + rr] = (1.f - zg) * n + zg * u;
    float r2 = sigmoidf_(gu[384 + rr] + bii[rr] + gv[384 + rr] + bih[rr]);
    float z2 = sigmoidf_(gu[512 + rr] + bii[128 + rr] + gv[512 + rr] + bih[128 + rr]);
    float n2 = tanhf(gu[640 + rr] + bii[256 + rr] + r2 * (gv[640 + rr] + bih[256 + rr]));
    float v = Xv[(size_t)e * EMB + rr];
    NV[(size_t)t * EMB + rr] = (1.f - z2) * n2 + z2 * v;
}

// ---------------------------------------------------------------------------
// Kernel 4: lev>=2 events (~15). One block per component, sequential in t.
// #pragma unroll 1 on mat/b loops is LOAD-BEARING: full unroll hoists 12x16
// float4 weight loads -> scratch spill (rounds 5/6: VGPR=256, 78-106 MB
// WRITE_SIZE, 100% spill-BW-bound).
// ---------------------------------------------------------------------------
__global__ __launch_bounds__(256) void tail2_kernel(
    const float* __restrict__ U0,  const float* __restrict__ V0,
    const float* __restrict__ Wui, const float* __restrict__ Wuh,
    const float* __restrict__ bui, const float* __restrict__ buh,
    const float* __restrict__ Wii, const float* __restrict__ Wih,
    const float* __restrict__ bii, const float* __restrict__ bih,
    const int* __restrict__ uids,  const int* __restrict__ iids,
    const int* __restrict__ prevu, const int* __restrict__ previ,
    const int* __restrict__ tail2Order, const int* __restrict__ compStart,
    const Hdr* __restrict__ hdr,
    float* __restrict__ NU, float* __restrict__ NV)
{
    __shared__ __align__(16) float su[EMB];
    __shared__ __align__(16) float sv[EMB];
    __shared__ float gg[1536];
    int tid = threadIdx.x;
    int ncomp = hdr->ncomp2;

    for (int c = blockIdx.x; c < ncomp; c += gridDim.x) {
        int kb = compStart[c], ke = compStart[c + 1];
        for (int k = kb; k < ke; ++k) {
            int t = tail2Order[k];
            int pu = prevu[t], pi = previ[t];
            const float* up = (pu < 0) ? U0 + (size_t)uids[t] * EMB : NU + (size_t)pu * EMB;
            const float* vp = (pi < 0) ? V0 + (size_t)iids[t] * EMB : NV + (size_t)pi * EMB;
            __syncthreads();
            if (tid < EMB) su[tid] = up[tid];
            else           sv[tid - EMB] = vp[tid - EMB];
            __syncthreads();

            int g = tid >> 4, j = tid & 15;
            #pragma unroll 1
            for (int mat = 0; mat < 4; ++mat) {
                const float* W = (mat == 0) ? Wui : (mat == 1) ? Wuh : (mat == 2) ? Wii : Wih;
                const float* x = (mat == 1 || mat == 2) ? su : sv;
                const float4* x4 = (const float4*)x;
                float4 xa = x4[2 * j], xb = x4[2 * j + 1];
                #pragma unroll 1
                for (int b = 0; b < 3; ++b) {
                    int rbase = g * 24 + b * 8;
                    float4 w0[8], w1[8];
                    #pragma unroll
                    for (int q = 0; q < 8; ++q) {
                        const float4* W4 = (const float4*)(W + (size_t)(rbase + q) * EMB);
                        w0[q] = W4[2 * j]; w1[q] = W4[2 * j + 1];
                    }
                    #pragma unroll
                    for (int q = 0; q < 8; ++q) {
                        float s = w0[q].x * xa.x + w0[q].y * xa.y
                                + w0[q].z * xa.z + w0[q].w * xa.w
                                + w1[q].x * xb.x + w1[q].y * xb.y
                                + w1[q].z * xb.z + w1[q].w * xb.w;
                        s += __shfl_xor(s, 1); s += __shfl_xor(s, 2);
                        s += __shfl_xor(s, 4); s += __shfl_xor(s, 8);
                        if (j == q) gg[mat * 384 + rbase + q] = s;
                    }
                }
            }
            __syncthreads();

            if (tid < EMB) {
                int e = tid;
                float r_ = sigmoidf_(gg[e] + bui[e] + gg[384 + e] + buh[e]);
                float z_ = sigmoidf_(gg[128 + e] + bui[128 + e] + gg[512 + e] + buh[128 + e]);
                float n_ = tanhf(gg[256 + e] + bui[256 + e] + r_ * (gg[640 + e] + buh[256 + e]));
                NU[(size_t)t * EMB + e] = (1.f - z_) * n_ + z_ * su[e];
            } else {
                int e = tid - EMB;
                float r_ = sigmoidf_(gg[768 + e] + bii[e] + gg[1152 + e] + bih[e]);
                float z_ = sigmoidf_(gg[896 + e] + bii[128 + e] + gg[1280 + e] + bih[128 + e]);
                float n_ = tanhf(gg[1024 + e] + bii[256 + e] + r_ * (gg[1408 + e] + bih[256 + e]));
                NV[(size_t)t * EMB + e] = (1.f - z_) * n_ + z_ * sv[e];
            }
        }
    }
}

// ---------------------------------------------------------------------------
// Kernel 5a: gather INPUT u,v for ALL events into XAu/XAv + loss output.
// ---------------------------------------------------------------------------
__global__ __launch_bounds__(256) void gatherall_kernel(
    const float* __restrict__ U0, const float* __restrict__ V0,
    const int* __restrict__ uids, const int* __restrict__ iids,
    const int* __restrict__ prevu, const int* __restrict__ previ,
    const float* __restrict__ NU, const float* __restrict__ NV,
    float* __restrict__ XAu, float* __restrict__ XAv,
    float* __restrict__ out, int nev)
{
    int sub = threadIdx.x >> 5;
    int lane = threadIdx.x & 31;
    int t = blockIdx.x * 8 + sub;
    if (t >= nev) return;
    int pu = prevu[t], pi = previ[t];
    const float4* up = (const float4*)(pu < 0 ?
        U0 + (size_t)uids[t] * EMB : NU + (size_t)pu * EMB);
    const float4* vp = (const float4*)(pi < 0 ?
        V0 + (size_t)iids[t] * EMB : NV + (size_t)pi * EMB);
    float4 a = up[lane], c = vp[lane];
    ((float4*)(XAu + (size_t)t * EMB))[lane] = a;
    ((float4*)(XAv + (size_t)t * EMB))[lane] = c;
    float dp = a.x * c.x + a.y * c.y + a.z * c.z + a.w * c.w;
    dp += __shfl_xor(dp, 1); dp += __shfl_xor(dp, 2);
    dp += __shfl_xor(dp, 4); dp += __shfl_xor(dp, 8);
    dp += __shfl_xor(dp, 16);
    if (lane == 0) out[2 * (size_t)t] = -logf(softplusf_(dp) + 1e-10f);
}

// ---------------------------------------------------------------------------
// Kernel 5b: T1 GEMM. H1 = relu([XAu|XAv] @ T1w^T + b). K=256 in 4 chunks.
// ---------------------------------------------------------------------------
__global__ __launch_bounds__(256, 4) void t1_gemm_kernel(
    const float* __restrict__ XAu, const float* __restrict__ XAv,
    const float* __restrict__ T1w, const float* __restrict__ T1b,
    float* __restrict__ H1, int nev)
{
    __shared__ float4 Xs[1024];
    __shared__ float4 Ws[1024];
    int ev0 = blockIdx.x * 64;
    int row0 = blockIdx.y * 64;
    int tid = threadIdx.x;
    int e0 = (tid >> 4) * 4, r0 = (tid & 15) * 4;
    int sx = (e0 >> 2) & 7, sw = (r0 >> 2) & 7;
    float acc[4][4] = {};
    const float4* W4 = (const float4*)T1w;

    for (int kh = 0; kh < 4; ++kh) {
        const float4* X4 = (const float4*)((kh < 2) ? XAu : XAv);
        int khh = kh & 1;
        __syncthreads();
        #pragma unroll
        for (int p = 0; p < 4; ++p) {
            int q = p * 256 + tid;
            int r = q >> 4, c4 = q & 15;
            int sr = (r >> 2) & 7;
            Xs[r * 16 + (c4 ^ sr)] = X4[(size_t)(ev0 + r) * 32 + khh * 16 + c4];
            Ws[r * 16 + (c4 ^ sr)] = W4[(size_t)(row0 + r) * 64 + kh * 16 + c4];
        }
        __syncthreads();
        #pragma unroll 4
        for (int k4 = 0; k4 < 16; ++k4) {
            float4 xa[4], wb[4];
            #pragma unroll
            for (int i = 0; i < 4; ++i) xa[i] = Xs[(e0 + i) * 16 + (k4 ^ sx)];
            #pragma unroll
            for (int jj = 0; jj < 4; ++jj) wb[jj] = Ws[(r0 + jj) * 16 + (k4 ^ sw)];
            #pragma unroll
            for (int i = 0; i < 4; ++i) {
                #pragma unroll
                for (int jj = 0; jj < 4; ++jj) {
                    acc[i][jj] = fmaf(xa[i].x, wb[jj].x, acc[i][jj]);
                    acc[i][jj] = fmaf(xa[i].y, wb[jj].y, acc[i][jj]);
                    acc[i][jj] = fmaf(xa[i].z, wb[jj].z, acc[i][jj]);
                    acc[i][jj] = fmaf(xa[i].w, wb[jj].w, acc[i][jj]);
                }
            }
        }
    }
    int col0 = row0 + r0;
    float b0 = T1b[col0], b1 = T1b[col0 + 1], b2 = T1b[col0 + 2], b3 = T1b[col0 + 3];
    #pragma unroll
    for (int i = 0; i < 4; ++i) {
        float4 v;
        v.x = fmaxf(acc[i][0] + b0, 0.f);
        v.y = fmaxf(acc[i][1] + b1, 0.f);
        v.z = fmaxf(acc[i][2] + b2, 0.f);
        v.w = fmaxf(acc[i][3] + b3, 0.f);
        *(float4*)&H1[(size_t)(ev0 + e0 + i) * EMB + col0] = v;
    }
}

// ---------------------------------------------------------------------------
// Kernel 5c: T2 + T3 + sigmoid. 16 events per block; T2w staged in LDS.
// ---------------------------------------------------------------------------
__global__ __launch_bounds__(256) void t2t3_kernel(
    const float* __restrict__ H1,
    const float* __restrict__ T2w, const float* __restrict__ T2b,
    const float* __restrict__ T3w, const float* __restrict__ T3b,
    float* __restrict__ out, int nev)
{
    __shared__ __align__(16) float w2s[32][132];
    __shared__ __align__(16) float h1s[16][132];
    __shared__ float h2s[16][36];
    int tid = threadIdx.x;
    int ev = tid >> 4, j = tid & 15;
    int t = blockIdx.x * 16 + ev;

    {
        const float4* s2 = (const float4*)T2w;
        #pragma unroll
        for (int i = 0; i < 4; ++i) {
            int q = i * 256 + tid;
            int r = q >> 5, c4 = q & 31;
            *(float4*)&w2s[r][c4 * 4] = s2[q];
        }
    }
    {
        const float4* h4 = (const float4*)(H1 + (size_t)(blockIdx.x * 16 + ev) * EMB);
        *(float4*)&h1s[ev][8 * j]     = h4[2 * j];
        *(float4*)&h1s[ev][8 * j + 4] = h4[2 * j + 1];
    }
    __syncthreads();

    float acc0 = T2b[2 * j], acc1 = T2b[2 * j + 1];
    const float4* wr0 = (const float4*)&w2s[2 * j][0];
    const float4* wr1 = (const float4*)&w2s[2 * j + 1][0];
    const float4* xh = (const float4*)&h1s[ev][0];
    #pragma unroll
    for (int k = 0; k < 32; ++k) {
        float4 x = xh[k], a = wr0[k], b = wr1[k];
        acc0 = fmaf(a.x, x.x, acc0); acc0 = fmaf(a.y, x.y, acc0);
        acc0 = fmaf(a.z, x.z, acc0); acc0 = fmaf(a.w, x.w, acc0);
        acc1 = fmaf(b.x, x.x, acc1); acc1 = fmaf(b.y, x.y, acc1);
        acc1 = fmaf(b.z, x.z, acc1); acc1 = fmaf(b.w, x.w, acc1);
    }
    h2s[ev][2 * j]     = fmaxf(acc0, 0.f);
    h2s[ev][2 * j + 1] = fmaxf(acc1, 0.f);
    __syncthreads();

    float p = T3w[2 * j] * h2s[ev][2 * j] + T3w[2 * j + 1] * h2s[ev][2 * j + 1];
    p += __shfl_xor(p, 1); p += __shfl_xor(p, 2);
    p += __shfl_xor(p, 4); p += __shfl_xor(p, 8);
    if (j == 0 && t < nev)
        out[2 * (size_t)t + 1] = sigmoidf_(p + T3b[0]);
}

// ---------------------------------------------------------------------------
extern "C" void kernel_launch(void* const* d_in, const int* in_sizes, int n_in,
                              void* d_out, int out_size, void* d_ws, size_t ws_size,
                              hipStream_t stream)
{
    const float* U0  = (const float*)d_in[0];
    const float* V0  = (const float*)d_in[1];
    const float* Wui = (const float*)d_in[2];
    const float* Wuh = (const float*)d_in[3];
    const float* bui = (const float*)d_in[4];
    const float* buh = (const float*)d_in[5];
    const float* Wii = (const float*)d_in[6];
    const float* Wih = (const float*)d_in[7];
    const float* bii = (const float*)d_in[8];
    const float* bih = (const float*)d_in[9];
    const float* T1w = (const float*)d_in[10];
    const float* T1b = (const float*)d_in[11];
    const float* T2w = (const float*)d_in[12];
    const float* T2b = (const float*)d_in[13];
    const float* T3w = (const float*)d_in[14];
    const float* T3b = (const float*)d_in[15];
    const int* uids  = (const int*)d_in[16];
    const int* iids  = (const int*)d_in[17];
    int nev = in_sizes[16];

    char* ws = (char*)d_ws;
    int* base = (int*)ws;
    int* prevu      = base;                 // MAXEV
    int* previ      = base + MAXEV;         // MAXEV
    int* order0     = base + 2 * MAXEV;     // MAXEV
    int* order1     = base + 3 * MAXEV;     // MAXEV
    int* tail2Order = base + 4 * MAXEV;     // MAXEV
    int* compStart  = base + 5 * MAXEV;     // MAXEV+2
    Hdr* hdr        = (Hdr*)(base + 6 * MAXEV + 4);
    float* NU = (float*)(ws + (160 << 10));            // 2 MB
    float* NV = NU + (size_t)MAXEV * EMB;              // 2 MB
    float* Xu = NV + (size_t)MAXEV * EMB;              // 2 MB (reused as XAu)
    float* Xv = Xu + (size_t)MAXEV * EMB;              // 2 MB (reused as XAv)
    float* Gu = Xv + (size_t)MAXEV * EMB;              // 12.6 MB (reused as H1)
    float* Gv = Gu + (size_t)MAXEV * 768;              // 12.6 MB
    float* out = (float*)d_out;

    prev_kernel<<<nev, 64, 0, stream>>>(uids, iids, prevu, previ, nev);
    setup_kernel<<<1, 1024, 0, stream>>>(prevu, previ, order0, order1,
                                         tail2Order, compStart, hdr, nev);

    // Pass A: level-0 events (read pristine tables)
    gatherx_kernel<<<(MAXEV + 7) / 8, 256, 0, stream>>>(
        U0, V0, uids, iids, prevu, previ, NU, NV, order0, &hdr->nl0, Xu, Xv);
    gate_gemm_kernel<<<dim3(MAXEV / 64, 12, 2), 256, 0, stream>>>(
        Xu, Xv, Wuh, Wii, Wui, Wih, &hdr->nl0, Gu, Gv);
    combine_kernel<<<(MAXEV + 1) / 2, 256, 0, stream>>>(
        Gu, Gv, Xu, Xv, bui, buh, bii, bih, order0, &hdr->nl0, NU, NV);

    // Pass B: level-1 events (preds all level-0, visible by stream order)
    gatherx_kernel<<<(MAXEV + 7) / 8, 256, 0, stream>>>(
        U0, V0, uids, iids, prevu, previ, NU, NV, order1, &hdr->nl1, Xu, Xv);
    gate_gemm_kernel<<<dim3(MAXEV / 64, 12, 2), 256, 0, stream>>>(
        Xu, Xv, Wuh, Wii, Wui, Wih, &hdr->nl1, Gu, Gv);
    combine_kernel<<<(MAXEV + 1) / 2, 256, 0, stream>>>(
        Gu, Gv, Xu, Xv, bui, buh, bii, bih, order1, &hdr->nl1, NU, NV);

    // lev>=2 remainder: component-serial
    tail2_kernel<<<256, 256, 0, stream>>>(
        U0, V0, Wui, Wuh, bui, buh, Wii, Wih, bii, bih,
        uids, iids, prevu, previ, tail2Order, compStart, hdr, NU, NV);

    float* XAu = Xu;
    float* XAv = Xv;
    float* H1  = Gu;
    gatherall_kernel<<<(nev + 7) / 8, 256, 0, stream>>>(
        U0, V0, uids, iids, prevu, previ, NU, NV, XAu, XAv, out, nev);
    t1_gemm_kernel<<<dim3((nev + 63) / 64, 2), 256, 0, stream>>>(
        XAu, XAv, T1w, T1b, H1, nev);
    t2t3_kernel<<<(nev + 15) / 16, 256, 0, stream>>>(
        H1, T2w, T2b, T3w, T3b, out, nev);
}

// Round 9
// 146.696 us; speedup vs baseline: 1.6834x; 1.0961x over previous
//
#include <hip/hip_runtime.h>
#include <math.h>

#define EMB 128
#define MAXEV 4096

struct Hdr { int nl0; int nl1; int ncomp2; };

__device__ __forceinline__ float sigmoidf_(float x) { return 1.0f / (1.0f + expf(-x)); }
__device__ __forceinline__ float softplusf_(float x) {
    return (x > 0.f) ? x + log1pf(expf(-x)) : log1pf(expf(x));
}

// ---------------------------------------------------------------------------
// Kernel 1: most recent earlier event with same user / item id.
// ---------------------------------------------------------------------------
__global__ __launch_bounds__(64) void prev_kernel(
    const int* __restrict__ uids, const int* __restrict__ iids,
    int* __restrict__ prevu, int* __restrict__ previ, int nev)
{
    int t = blockIdx.x;
    if (t >= nev) return;
    int lane = threadIdx.x;
    int myu = uids[t], myi = iids[t];
    int bu = -1, bi = -1;
    for (int j = lane; j < t; j += 64) {
        if (uids[j] == myu) bu = j;
        if (iids[j] == myi) bi = j;
    }
    for (int off = 32; off; off >>= 1) {
        bu = max(bu, __shfl_xor(bu, off));
        bi = max(bi, __shfl_xor(bi, off));
    }
    if (lane == 0) { prevu[t] = bu; previ[t] = bi; }
}

// ---------------------------------------------------------------------------
// Kernel 2 (single block): exact DAG levels (lev = 0 | 1+max(lev(preds))),
// partition into lev0 / lev1 / lev>=2; lev>=2 grouped by connected component
// (min-label, conservative) and sorted by (comp, t).
// ---------------------------------------------------------------------------
__global__ __launch_bounds__(1024) void setup_kernel(
    const int* __restrict__ prevu, const int* __restrict__ previ,
    int* __restrict__ order0, int* __restrict__ order1,
    int* __restrict__ tail2Order, int* __restrict__ compStart,
    Hdr* __restrict__ hdr, int nev)
{
    __shared__ int   lab[MAXEV];
    __shared__ int   tmpT[MAXEV];
    __shared__ int   skey[MAXEV];
    __shared__ short slev[MAXEV];
    __shared__ int   schanged, sn0, sn1, sn2;

    int tid = threadIdx.x;
    for (int t = tid; t < nev; t += 1024) { lab[t] = t; slev[t] = 0; }
    if (tid == 0) { sn0 = 0; sn1 = 0; sn2 = 0; }
    __syncthreads();

    for (int it = 0; it < nev; ++it) {
        if (tid == 0) schanged = 0;
        __syncthreads();
        for (int t = tid; t < nev; t += 1024) {
            int pu = prevu[t], pi = previ[t];
            int nl = 0;
            if (pu >= 0) nl = slev[pu] + 1;
            if (pi >= 0) { int c = slev[pi] + 1; nl = nl > c ? nl : c; }
            if (nl > (int)slev[t]) { slev[t] = (short)nl; schanged = 1; }
        }
        __syncthreads();
        if (!schanged) break;
        __syncthreads();
    }

    for (int it = 0; it < nev; ++it) {
        if (tid == 0) schanged = 0;
        __syncthreads();
        for (int t = tid; t < nev; t += 1024) {
            int m = lab[t];
            int pu = prevu[t], pi = previ[t];
            if (pu >= 0) m = min(m, lab[pu]);
            if (pi >= 0) m = min(m, lab[pi]);
            if (m < lab[t]) { atomicMin(&lab[t], m); schanged = 1; }
            if (pu >= 0 && m < lab[pu]) { atomicMin(&lab[pu], m); schanged = 1; }
            if (pi >= 0 && m < lab[pi]) { atomicMin(&lab[pi], m); schanged = 1; }
        }
        __syncthreads();
        if (!schanged) break;
        __syncthreads();
    }

    for (int t = tid; t < nev; t += 1024) {
        int l = slev[t];
        if (l == 0)      order0[atomicAdd(&sn0, 1)] = t;
        else if (l == 1) order1[atomicAdd(&sn1, 1)] = t;
        else             tmpT[atomicAdd(&sn2, 1)] = t;
    }
    __syncthreads();
    int n2 = sn2;

    for (int i = tid; i < n2; i += 1024)
        skey[i] = (lab[tmpT[i]] << 12) | tmpT[i];
    __syncthreads();

    for (int i = tid; i < n2; i += 1024) {
        int k = skey[i], r = 0;
        for (int j = 0; j < n2; ++j) r += (skey[j] < k);
        tail2Order[r] = tmpT[i];
        lab[r] = k;
    }
    __syncthreads();

    if (tid == 0) {
        int nc = 0;
        for (int i = 0; i < n2; ++i)
            if (i == 0 || (lab[i] >> 12) != (lab[i - 1] >> 12))
                compStart[nc++] = i;
        compStart[nc] = n2;
        hdr->nl0 = sn0;
        hdr->nl1 = sn1;
        hdr->ncomp2 = nc;
    }
}

// ---------------------------------------------------------------------------
// Kernel 3a (both passes): gather event inputs (via prev indirection) into
// dense Xu/Xv [NP64,128], zero-padded to a multiple of 64 rows.
// ---------------------------------------------------------------------------
__global__ __launch_bounds__(256) void gatherx_kernel(
    const float* __restrict__ U0, const float* __restrict__ V0,
    const int* __restrict__ uids, const int* __restrict__ iids,
    const int* __restrict__ prevu, const int* __restrict__ previ,
    const float* __restrict__ NU, const float* __restrict__ NV,
    const int* __restrict__ order, const int* __restrict__ cnt_p,
    float* __restrict__ Xu, float* __restrict__ Xv)
{
    int cnt = *cnt_p;
    int NP64 = (cnt + 63) & ~63;
    int sub = threadIdx.x >> 5;
    int lane = threadIdx.x & 31;
    int e = blockIdx.x * 8 + sub;
    if (e >= NP64) return;
    float4* xu = (float4*)(Xu + (size_t)e * EMB);
    float4* xv = (float4*)(Xv + (size_t)e * EMB);
    if (e < cnt) {
        int t = order[e];
        int pu = prevu[t], pi = previ[t];
        const float4* up = (const float4*)(pu < 0 ?
            U0 + (size_t)uids[t] * EMB : NU + (size_t)pu * EMB);
        const float4* vp = (const float4*)(pi < 0 ?
            V0 + (size_t)iids[t] * EMB : NV + (size_t)pi * EMB);
        xu[lane] = up[lane];
        xv[lane] = vp[lane];
    } else {
        float4 zz = make_float4(0.f, 0.f, 0.f, 0.f);
        xu[lane] = zz;
        xv[lane] = zz;
    }
}

// ---------------------------------------------------------------------------
// Kernel 3b (both passes): gate GEMM. G_u = Xu @ [Wuh;Wii]^T,
// G_v = Xv @ [Wui;Wih]^T. 64x64 tile, K=128 in two halves, XOR-swizzled LDS,
// 4x4 register tile.
// ---------------------------------------------------------------------------
__global__ __launch_bounds__(256, 4) void gate_gemm_kernel(
    const float* __restrict__ Xu, const float* __restrict__ Xv,
    const float* __restrict__ Wuh, const float* __restrict__ Wii,
    const float* __restrict__ Wui, const float* __restrict__ Wih,
    const int* __restrict__ cnt_p,
    float* __restrict__ Gu, float* __restrict__ Gv)
{
    __shared__ float4 Xs[1024];
    __shared__ float4 Ws[1024];
    int cnt = *cnt_p;
    int NP64 = (cnt + 63) & ~63;
    int ev0 = blockIdx.x * 64;
    if (ev0 >= NP64) return;
    int z = blockIdx.z;
    int j = blockIdx.y;
    const float* X  = z ? Xv : Xu;
    const float* W1 = z ? Wui : Wuh;
    const float* W2 = z ? Wih : Wii;
    float* G = z ? Gv : Gu;
    const float* Wsrc = (j < 6) ? W1 : W2;
    int row0 = ((j < 6) ? j : j - 6) * 64;

    int tid = threadIdx.x;
    int e0 = (tid >> 4) * 4, r0 = (tid & 15) * 4;
    int sx = (e0 >> 2) & 7, sw = (r0 >> 2) & 7;
    float acc[4][4] = {};
    const float4* X4 = (const float4*)X;
    const float4* W4 = (const float4*)Wsrc;

    for (int kh = 0; kh < 2; ++kh) {
        __syncthreads();
        #pragma unroll
        for (int p = 0; p < 4; ++p) {
            int q = p * 256 + tid;
            int r = q >> 4, c4 = q & 15;
            int sr = (r >> 2) & 7;
            Xs[r * 16 + (c4 ^ sr)] = X4[(size_t)(ev0 + r) * 32 + kh * 16 + c4];
            Ws[r * 16 + (c4 ^ sr)] = W4[(size_t)(row0 + r) * 32 + kh * 16 + c4];
        }
        __syncthreads();
        #pragma unroll 4
        for (int k4 = 0; k4 < 16; ++k4) {
            float4 xa[4], wb[4];
            #pragma unroll
            for (int i = 0; i < 4; ++i) xa[i] = Xs[(e0 + i) * 16 + (k4 ^ sx)];
            #pragma unroll
            for (int jj = 0; jj < 4; ++jj) wb[jj] = Ws[(r0 + jj) * 16 + (k4 ^ sw)];
            #pragma unroll
            for (int i = 0; i < 4; ++i) {
                #pragma unroll
                for (int jj = 0; jj < 4; ++jj) {
                    acc[i][jj] = fmaf(xa[i].x, wb[jj].x, acc[i][jj]);
                    acc[i][jj] = fmaf(xa[i].y, wb[jj].y, acc[i][jj]);
                    acc[i][jj] = fmaf(xa[i].z, wb[jj].z, acc[i][jj]);
                    acc[i][jj] = fmaf(xa[i].w, wb[jj].w, acc[i][jj]);
                }
            }
        }
    }
    int col0 = j * 64 + r0;
    #pragma unroll
    for (int i = 0; i < 4; ++i) {
        float4 v = make_float4(acc[i][0], acc[i][1], acc[i][2], acc[i][3]);
        *(float4*)&G[(size_t)(ev0 + e0 + i) * 768 + col0] = v;
    }
}

// ---------------------------------------------------------------------------
// Kernel 3c (both passes): gate combine -> NU/NV.
// ---------------------------------------------------------------------------
__global__ __launch_bounds__(256) void combine_kernel(
    const float* __restrict__ Gu, const float* __restrict__ Gv,
    const float* __restrict__ Xu, const float* __restrict__ Xv,
    const float* __restrict__ bui, const float* __restrict__ buh,
    const float* __restrict__ bii, const float* __restrict__ bih,
    const int* __restrict__ order, const int* __restrict__ cnt_p,
    float* __restrict__ NU, float* __restrict__ NV)
{
    int cnt = *cnt_p;
    int e = blockIdx.x * 2 + (threadIdx.x >> 7);
    int rr = threadIdx.x & 127;
    if (e >= cnt) return;
    int t = order[e];
    const float* gu = Gu + (size_t)e * 768;
    const float* gv = Gv + (size_t)e * 768;
    float r = sigmoidf_(gv[rr] + bui[rr] + gu[rr] + buh[rr]);
    float zg = sigmoidf_(gv[128 + rr] + bui[128 + rr] + gu[128 + rr] + buh[128 + rr]);
    float n = tanhf(gv[256 + rr] + bui[256 + rr] + r * (gu[256 + rr] + buh[256 + rr]));
    float u = Xu[(size_t)e * EMB + rr];
    NU[(size_t)t * EMB + rr] = (1.f - zg) * n + zg * u;
    float r2 = sigmoidf_(gu[384 + rr] + bii[rr] + gv[384 + rr] + bih[rr]);
    float z2 = sigmoidf_(gu[512 + rr] + bii[128 + rr] + gv[512 + rr] + bih[128 + rr]);
    float n2 = tanhf(gu[640 + rr] + bii[256 + rr] + r2 * (gv[640 + rr] + bih[256 + rr]));
    float v = Xv[(size_t)e * EMB + rr];
    NV[(size_t)t * EMB + rr] = (1.f - z2) * n2 + z2 * v;
}

// ---------------------------------------------------------------------------
// Kernel 4: lev>=2 events (~15). One 1024-thread block per component,
// sequential in t. 64 groups x 16 lanes: each group owns 24 rows (16 groups
// per GRU matrix -> mat wave-uniform), batches of 8 -> only 3 serial L2
// round trips per event (vs 12 at 256 threads). #pragma unroll 1 on the
// batch loop is LOAD-BEARING (rounds 5/6: full unroll -> 768 live regs ->
// scratch spill, 78-106 MB WRITE_SIZE, 100% spill-BW-bound).
// ---------------------------------------------------------------------------
__global__ __launch_bounds__(1024) void tail2_kernel(
    const float* __restrict__ U0,  const float* __restrict__ V0,
    const float* __restrict__ Wui, const float* __restrict__ Wuh,
    const float* __restrict__ bui, const float* __restrict__ buh,
    const float* __restrict__ Wii, const float* __restrict__ Wih,
    const float* __restrict__ bii, const float* __restrict__ bih,
    const int* __restrict__ uids,  const int* __restrict__ iids,
    const int* __restrict__ prevu, const int* __restrict__ previ,
    const int* __restrict__ tail2Order, const int* __restrict__ compStart,
    const Hdr* __restrict__ hdr,
    float* __restrict__ NU, float* __restrict__ NV)
{
    __shared__ __align__(16) float su[EMB];
    __shared__ __align__(16) float sv[EMB];
    __shared__ float gg[1536];
    int tid = threadIdx.x;
    int ncomp = hdr->ncomp2;

    int g = tid >> 4, j = tid & 15;       // 64 groups x 16 lanes
    int mat = g >> 4;                     // 16 groups per matrix
    const float* W = (mat == 0) ? Wui : (mat == 1) ? Wuh : (mat == 2) ? Wii : Wih;

    for (int c = blockIdx.x; c < ncomp; c += gridDim.x) {
        int kb = compStart[c], ke = compStart[c + 1];
        for (int k = kb; k < ke; ++k) {
            int t = tail2Order[k];
            int pu = prevu[t], pi = previ[t];
            const float* up = (pu < 0) ? U0 + (size_t)uids[t] * EMB : NU + (size_t)pu * EMB;
            const float* vp = (pi < 0) ? V0 + (size_t)iids[t] * EMB : NV + (size_t)pi * EMB;
            __syncthreads();   // protect su/sv/gg reuse across events
            if (tid < EMB)        su[tid] = up[tid];
            else if (tid < 2*EMB) sv[tid - EMB] = vp[tid - EMB];
            __syncthreads();

            const float* x = (mat == 1 || mat == 2) ? su : sv;
            const float4* x4 = (const float4*)x;
            float4 xa = x4[2 * j], xb = x4[2 * j + 1];
            #pragma unroll 1
            for (int b = 0; b < 3; ++b) {
                int rbase = (g & 15) * 24 + b * 8;     // 0..376 within mat
                float4 w0[8], w1[8];
                #pragma unroll
                for (int q = 0; q < 8; ++q) {
                    const float4* W4 = (const float4*)(W + (size_t)(rbase + q) * EMB);
                    w0[q] = W4[2 * j]; w1[q] = W4[2 * j + 1];
                }
                #pragma unroll
                for (int q = 0; q < 8; ++q) {
                    float s = w0[q].x * xa.x + w0[q].y * xa.y
                            + w0[q].z * xa.z + w0[q].w * xa.w
                            + w1[q].x * xb.x + w1[q].y * xb.y
                            + w1[q].z * xb.z + w1[q].w * xb.w;
                    s += __shfl_xor(s, 1); s += __shfl_xor(s, 2);
                    s += __shfl_xor(s, 4); s += __shfl_xor(s, 8);
                    if (j == q) gg[mat * 384 + rbase + q] = s;
                }
            }
            __syncthreads();

            if (tid < EMB) {
                int e = tid;
                float r_ = sigmoidf_(gg[e] + bui[e] + gg[384 + e] + buh[e]);
                float z_ = sigmoidf_(gg[128 + e] + bui[128 + e] + gg[512 + e] + buh[128 + e]);
                float n_ = tanhf(gg[256 + e] + bui[256 + e] + r_ * (gg[640 + e] + buh[256 + e]));
                NU[(size_t)t * EMB + e] = (1.f - z_) * n_ + z_ * su[e];
            } else if (tid < 2*EMB) {
                int e = tid - EMB;
                float r_ = sigmoidf_(gg[768 + e] + bii[e] + gg[1152 + e] + bih[e]);
                float z_ = sigmoidf_(gg[896 + e] + bii[128 + e] + gg[1280 + e] + bih[128 + e]);
                float n_ = tanhf(gg[1024 + e] + bii[256 + e] + r_ * (gg[1408 + e] + bih[256 + e]));
                NV[(size_t)t * EMB + e] = (1.f - z_) * n_ + z_ * sv[e];
            }
        }
    }
}

// ---------------------------------------------------------------------------
// Kernel 5a: gather INPUT u,v for ALL events into XAu/XAv + loss output.
// ---------------------------------------------------------------------------
__global__ __launch_bounds__(256) void gatherall_kernel(
    const float* __restrict__ U0, const float* __restrict__ V0,
    const int* __restrict__ uids, const int* __restrict__ iids,
    const int* __restrict__ prevu, const int* __restrict__ previ,
    const float* __restrict__ NU, const float* __restrict__ NV,
    float* __restrict__ XAu, float* __restrict__ XAv,
    float* __restrict__ out, int nev)
{
    int sub = threadIdx.x >> 5;
    int lane = threadIdx.x & 31;
    int t = blockIdx.x * 8 + sub;
    if (t >= nev) return;
    int pu = prevu[t], pi = previ[t];
    const float4* up = (const float4*)(pu < 0 ?
        U0 + (size_t)uids[t] * EMB : NU + (size_t)pu * EMB);
    const float4* vp = (const float4*)(pi < 0 ?
        V0 + (size_t)iids[t] * EMB : NV + (size_t)pi * EMB);
    float4 a = up[lane], c = vp[lane];
    ((float4*)(XAu + (size_t)t * EMB))[lane] = a;
    ((float4*)(XAv + (size_t)t * EMB))[lane] = c;
    float dp = a.x * c.x + a.y * c.y + a.z * c.z + a.w * c.w;
    dp += __shfl_xor(dp, 1); dp += __shfl_xor(dp, 2);
    dp += __shfl_xor(dp, 4); dp += __shfl_xor(dp, 8);
    dp += __shfl_xor(dp, 16);
    if (lane == 0) out[2 * (size_t)t] = -logf(softplusf_(dp) + 1e-10f);
}

// ---------------------------------------------------------------------------
// Kernel 5b: T1 GEMM. H1 = relu([XAu|XAv] @ T1w^T + b). K=256 in 4 chunks.
// ---------------------------------------------------------------------------
__global__ __launch_bounds__(256, 4) void t1_gemm_kernel(
    const float* __restrict__ XAu, const float* __restrict__ XAv,
    const float* __restrict__ T1w, const float* __restrict__ T1b,
    float* __restrict__ H1, int nev)
{
    __shared__ float4 Xs[1024];
    __shared__ float4 Ws[1024];
    int ev0 = blockIdx.x * 64;
    int row0 = blockIdx.y * 64;
    int tid = threadIdx.x;
    int e0 = (tid >> 4) * 4, r0 = (tid & 15) * 4;
    int sx = (e0 >> 2) & 7, sw = (r0 >> 2) & 7;
    float acc[4][4] = {};
    const float4* W4 = (const float4*)T1w;

    for (int kh = 0; kh < 4; ++kh) {
        const float4* X4 = (const float4*)((kh < 2) ? XAu : XAv);
        int khh = kh & 1;
        __syncthreads();
        #pragma unroll
        for (int p = 0; p < 4; ++p) {
            int q = p * 256 + tid;
            int r = q >> 4, c4 = q & 15;
            int sr = (r >> 2) & 7;
            Xs[r * 16 + (c4 ^ sr)] = X4[(size_t)(ev0 + r) * 32 + khh * 16 + c4];
            Ws[r * 16 + (c4 ^ sr)] = W4[(size_t)(row0 + r) * 64 + kh * 16 + c4];
        }
        __syncthreads();
        #pragma unroll 4
        for (int k4 = 0; k4 < 16; ++k4) {
            float4 xa[4], wb[4];
            #pragma unroll
            for (int i = 0; i < 4; ++i) xa[i] = Xs[(e0 + i) * 16 + (k4 ^ sx)];
            #pragma unroll
            for (int jj = 0; jj < 4; ++jj) wb[jj] = Ws[(r0 + jj) * 16 + (k4 ^ sw)];
            #pragma unroll
            for (int i = 0; i < 4; ++i) {
                #pragma unroll
                for (int jj = 0; jj < 4; ++jj) {
                    acc[i][jj] = fmaf(xa[i].x, wb[jj].x, acc[i][jj]);
                    acc[i][jj] = fmaf(xa[i].y, wb[jj].y, acc[i][jj]);
                    acc[i][jj] = fmaf(xa[i].z, wb[jj].z, acc[i][jj]);
                    acc[i][jj] = fmaf(xa[i].w, wb[jj].w, acc[i][jj]);
                }
            }
        }
    }
    int col0 = row0 + r0;
    float b0 = T1b[col0], b1 = T1b[col0 + 1], b2 = T1b[col0 + 2], b3 = T1b[col0 + 3];
    #pragma unroll
    for (int i = 0; i < 4; ++i) {
        float4 v;
        v.x = fmaxf(acc[i][0] + b0, 0.f);
        v.y = fmaxf(acc[i][1] + b1, 0.f);
        v.z = fmaxf(acc[i][2] + b2, 0.f);
        v.w = fmaxf(acc[i][3] + b3, 0.f);
        *(float4*)&H1[(size_t)(ev0 + e0 + i) * EMB + col0] = v;
    }
}

// ---------------------------------------------------------------------------
// Kernel 5c: T2 + T3 + sigmoid. 16 events per block; T2w staged in LDS.
// ---------------------------------------------------------------------------
__global__ __launch_bounds__(256) void t2t3_kernel(
    const float* __restrict__ H1,
    const float* __restrict__ T2w, const float* __restrict__ T2b,
    const float* __restrict__ T3w, const float* __restrict__ T3b,
    float* __restrict__ out, int nev)
{
    __shared__ __align__(16) float w2s[32][132];
    __shared__ __align__(16) float h1s[16][132];
    __shared__ float h2s[16][36];
    int tid = threadIdx.x;
    int ev = tid >> 4, j = tid & 15;
    int t = blockIdx.x * 16 + ev;

    {
        const float4* s2 = (const float4*)T2w;
        #pragma unroll
        for (int i = 0; i < 4; ++i) {
            int q = i * 256 + tid;
            int r = q >> 5, c4 = q & 31;
            *(float4*)&w2s[r][c4 * 4] = s2[q];
        }
    }
    {
        const float4* h4 = (const float4*)(H1 + (size_t)(blockIdx.x * 16 + ev) * EMB);
        *(float4*)&h1s[ev][8 * j]     = h4[2 * j];
        *(float4*)&h1s[ev][8 * j + 4] = h4[2 * j + 1];
    }
    __syncthreads();

    float acc0 = T2b[2 * j], acc1 = T2b[2 * j + 1];
    const float4* wr0 = (const float4*)&w2s[2 * j][0];
    const float4* wr1 = (const float4*)&w2s[2 * j + 1][0];
    const float4* xh = (const float4*)&h1s[ev][0];
    #pragma unroll
    for (int k = 0; k < 32; ++k) {
        float4 x = xh[k], a = wr0[k], b = wr1[k];
        acc0 = fmaf(a.x, x.x, acc0); acc0 = fmaf(a.y, x.y, acc0);
        acc0 = fmaf(a.z, x.z, acc0); acc0 = fmaf(a.w, x.w, acc0);
        acc1 = fmaf(b.x, x.x, acc1); acc1 = fmaf(b.y, x.y, acc1);
        acc1 = fmaf(b.z, x.z, acc1); acc1 = fmaf(b.w, x.w, acc1);
    }
    h2s[ev][2 * j]     = fmaxf(acc0, 0.f);
    h2s[ev][2 * j + 1] = fmaxf(acc1, 0.f);
    __syncthreads();

    float p = T3w[2 * j] * h2s[ev][2 * j] + T3w[2 * j + 1] * h2s[ev][2 * j + 1];
    p += __shfl_xor(p, 1); p += __shfl_xor(p, 2);
    p += __shfl_xor(p, 4); p += __shfl_xor(p, 8);
    if (j == 0 && t < nev)
        out[2 * (size_t)t + 1] = sigmoidf_(p + T3b[0]);
}

// ---------------------------------------------------------------------------
extern "C" void kernel_launch(void* const* d_in, const int* in_sizes, int n_in,
                              void* d_out, int out_size, void* d_ws, size_t ws_size,
                              hipStream_t stream)
{
    const float* U0  = (const float*)d_in[0];
    const float* V0  = (const float*)d_in[1];
    const float* Wui = (const float*)d_in[2];
    const float* Wuh = (const float*)d_in[3];
    const float* bui = (const float*)d_in[4];
    const float* buh = (const float*)d_in[5];
    const float* Wii = (const float*)d_in[6];
    const float* Wih = (const float*)d_in[7];
    const float* bii = (const float*)d_in[8];
    const float* bih = (const float*)d_in[9];
    const float* T1w = (const float*)d_in[10];
    const float* T1b = (const float*)d_in[11];
    const float* T2w = (const float*)d_in[12];
    const float* T2b = (const float*)d_in[13];
    const float* T3w = (const float*)d_in[14];
    const float* T3b = (const float*)d_in[15];
    const int* uids  = (const int*)d_in[16];
    const int* iids  = (const int*)d_in[17];
    int nev = in_sizes[16];

    char* ws = (char*)d_ws;
    int* base = (int*)ws;
    int* prevu      = base;                 // MAXEV
    int* previ      = base + MAXEV;         // MAXEV
    int* order0     = base + 2 * MAXEV;     // MAXEV
    int* order1     = base + 3 * MAXEV;     // MAXEV
    int* tail2Order = base + 4 * MAXEV;     // MAXEV
    int* compStart  = base + 5 * MAXEV;     // MAXEV+2
    Hdr* hdr        = (Hdr*)(base + 6 * MAXEV + 4);
    float* NU = (float*)(ws + (160 << 10));            // 2 MB
    float* NV = NU + (size_t)MAXEV * EMB;              // 2 MB
    float* Xu = NV + (size_t)MAXEV * EMB;              // 2 MB (reused as XAu)
    float* Xv = Xu + (size_t)MAXEV * EMB;              // 2 MB (reused as XAv)
    float* Gu = Xv + (size_t)MAXEV * EMB;              // 12.6 MB (reused as H1)
    float* Gv = Gu + (size_t)MAXEV * 768;              // 12.6 MB
    float* out = (float*)d_out;

    prev_kernel<<<nev, 64, 0, stream>>>(uids, iids, prevu, previ, nev);
    setup_kernel<<<1, 1024, 0, stream>>>(prevu, previ, order0, order1,
                                         tail2Order, compStart, hdr, nev);

    // Pass A: level-0 events (read pristine tables)
    gatherx_kernel<<<(MAXEV + 7) / 8, 256, 0, stream>>>(
        U0, V0, uids, iids, prevu, previ, NU, NV, order0, &hdr->nl0, Xu, Xv);
    gate_gemm_kernel<<<dim3(MAXEV / 64, 12, 2), 256, 0, stream>>>(
        Xu, Xv, Wuh, Wii, Wui, Wih, &hdr->nl0, Gu, Gv);
    combine_kernel<<<(MAXEV + 1) / 2, 256, 0, stream>>>(
        Gu, Gv, Xu, Xv, bui, buh, bii, bih, order0, &hdr->nl0, NU, NV);

    // Pass B: level-1 events (preds all level-0, visible by stream order)
    gatherx_kernel<<<(MAXEV + 7) / 8, 256, 0, stream>>>(
        U0, V0, uids, iids, prevu, previ, NU, NV, order1, &hdr->nl1, Xu, Xv);
    gate_gemm_kernel<<<dim3(MAXEV / 64, 12, 2), 256, 0, stream>>>(
        Xu, Xv, Wuh, Wii, Wui, Wih, &hdr->nl1, Gu, Gv);
    combine_kernel<<<(MAXEV + 1) / 2, 256, 0, stream>>>(
        Gu, Gv, Xu, Xv, bui, buh, bii, bih, order1, &hdr->nl1, NU, NV);

    // lev>=2 remainder: component-serial, 1024-thread blocks
    tail2_kernel<<<64, 1024, 0, stream>>>(
        U0, V0, Wui, Wuh, bui, buh, Wii, Wih, bii, bih,
        uids, iids, prevu, previ, tail2Order, compStart, hdr, NU, NV);

    float* XAu = Xu;
    float* XAv = Xv;
    float* H1  = Gu;
    gatherall_kernel<<<(nev + 7) / 8, 256, 0, stream>>>(
        U0, V0, uids, iids, prevu, previ, NU, NV, XAu, XAv, out, nev);
    t1_gemm_kernel<<<dim3((nev + 63) / 64, 2), 256, 0, stream>>>(
        XAu, XAv, T1w, T1b, H1, nev);
    t2t3_kernel<<<(nev + 15) / 16, 256, 0, stream>>>(
        H1, T2w, T2b, T3w, T3b, out, nev);
}

// Round 10
// 127.127 us; speedup vs baseline: 1.9426x; 1.1539x over previous
//
#include <hip/hip_runtime.h>
#include <math.h>

#define EMB 128
#define MAXEV 4096

struct Hdr { int nl0; int nl1; int ncomp2; };

typedef __attribute__((ext_vector_type(8))) short bf16x8;
typedef __attribute__((ext_vector_type(4))) float f32x4;

__device__ __forceinline__ float sigmoidf_(float x) { return 1.0f / (1.0f + expf(-x)); }
__device__ __forceinline__ float softplusf_(float x) {
    return (x > 0.f) ? x + log1pf(expf(-x)) : log1pf(expf(x));
}
__device__ __forceinline__ unsigned short f2bf(float f) {
    unsigned int u = __float_as_uint(f);
    u += 0x7FFFu + ((u >> 16) & 1u);          // round-to-nearest-even
    return (unsigned short)(u >> 16);
}

// ---------------------------------------------------------------------------
// Kernel 1: most recent earlier event with same user / item id.
// ---------------------------------------------------------------------------
__global__ __launch_bounds__(64) void prev_kernel(
    const int* __restrict__ uids, const int* __restrict__ iids,
    int* __restrict__ prevu, int* __restrict__ previ, int nev)
{
    int t = blockIdx.x;
    if (t >= nev) return;
    int lane = threadIdx.x;
    int myu = uids[t], myi = iids[t];
    int bu = -1, bi = -1;
    for (int j = lane; j < t; j += 64) {
        if (uids[j] == myu) bu = j;
        if (iids[j] == myi) bi = j;
    }
    for (int off = 32; off; off >>= 1) {
        bu = max(bu, __shfl_xor(bu, off));
        bi = max(bi, __shfl_xor(bi, off));
    }
    if (lane == 0) { prevu[t] = bu; previ[t] = bi; }
}

// ---------------------------------------------------------------------------
// Kernel 2 (single block): exact DAG levels, partition lev0/lev1/lev>=2;
// lev>=2 grouped by connected component and sorted by (comp, t).
// ---------------------------------------------------------------------------
__global__ __launch_bounds__(1024) void setup_kernel(
    const int* __restrict__ prevu, const int* __restrict__ previ,
    int* __restrict__ order0, int* __restrict__ order1,
    int* __restrict__ tail2Order, int* __restrict__ compStart,
    Hdr* __restrict__ hdr, int nev)
{
    __shared__ int   lab[MAXEV];
    __shared__ int   tmpT[MAXEV];
    __shared__ int   skey[MAXEV];
    __shared__ short slev[MAXEV];
    __shared__ int   schanged, sn0, sn1, sn2;

    int tid = threadIdx.x;
    for (int t = tid; t < nev; t += 1024) { lab[t] = t; slev[t] = 0; }
    if (tid == 0) { sn0 = 0; sn1 = 0; sn2 = 0; }
    __syncthreads();

    for (int it = 0; it < nev; ++it) {
        if (tid == 0) schanged = 0;
        __syncthreads();
        for (int t = tid; t < nev; t += 1024) {
            int pu = prevu[t], pi = previ[t];
            int nl = 0;
            if (pu >= 0) nl = slev[pu] + 1;
            if (pi >= 0) { int c = slev[pi] + 1; nl = nl > c ? nl : c; }
            if (nl > (int)slev[t]) { slev[t] = (short)nl; schanged = 1; }
        }
        __syncthreads();
        if (!schanged) break;
        __syncthreads();
    }

    for (int it = 0; it < nev; ++it) {
        if (tid == 0) schanged = 0;
        __syncthreads();
        for (int t = tid; t < nev; t += 1024) {
            int m = lab[t];
            int pu = prevu[t], pi = previ[t];
            if (pu >= 0) m = min(m, lab[pu]);
            if (pi >= 0) m = min(m, lab[pi]);
            if (m < lab[t]) { atomicMin(&lab[t], m); schanged = 1; }
            if (pu >= 0 && m < lab[pu]) { atomicMin(&lab[pu], m); schanged = 1; }
            if (pi >= 0 && m < lab[pi]) { atomicMin(&lab[pi], m); schanged = 1; }
        }
        __syncthreads();
        if (!schanged) break;
        __syncthreads();
    }

    for (int t = tid; t < nev; t += 1024) {
        int l = slev[t];
        if (l == 0)      order0[atomicAdd(&sn0, 1)] = t;
        else if (l == 1) order1[atomicAdd(&sn1, 1)] = t;
        else             tmpT[atomicAdd(&sn2, 1)] = t;
    }
    __syncthreads();
    int n2 = sn2;

    for (int i = tid; i < n2; i += 1024)
        skey[i] = (lab[tmpT[i]] << 12) | tmpT[i];
    __syncthreads();

    for (int i = tid; i < n2; i += 1024) {
        int k = skey[i], r = 0;
        for (int j = 0; j < n2; ++j) r += (skey[j] < k);
        tail2Order[r] = tmpT[i];
        lab[r] = k;
    }
    __syncthreads();

    if (tid == 0) {
        int nc = 0;
        for (int i = 0; i < n2; ++i)
            if (i == 0 || (lab[i] >> 12) != (lab[i - 1] >> 12))
                compStart[nc++] = i;
        compStart[nc] = n2;
        hdr->nl0 = sn0;
        hdr->nl1 = sn1;
        hdr->ncomp2 = nc;
    }
}

// ---------------------------------------------------------------------------
// Kernel 2b: convert the 4 GRU matrices + T1w to bf16 (once).
// grid (48, 5): y selects matrix; x covers float4 elements.
// ---------------------------------------------------------------------------
__global__ __launch_bounds__(256) void wcvt_kernel(
    const float* __restrict__ Wuh, const float* __restrict__ Wii,
    const float* __restrict__ Wui, const float* __restrict__ Wih,
    const float* __restrict__ T1w,
    unsigned short* __restrict__ wb_uh, unsigned short* __restrict__ wb_ii,
    unsigned short* __restrict__ wb_ui, unsigned short* __restrict__ wb_ih,
    unsigned short* __restrict__ t1wb)
{
    int m = blockIdx.y;
    const float* src = (m == 0) ? Wuh : (m == 1) ? Wii : (m == 2) ? Wui
                      : (m == 3) ? Wih : T1w;
    unsigned short* dst = (m == 0) ? wb_uh : (m == 1) ? wb_ii : (m == 2) ? wb_ui
                        : (m == 3) ? wb_ih : t1wb;
    int nf4 = (m < 4) ? (384 * EMB / 4) : (EMB * 256 / 4);
    int q = blockIdx.x * 256 + threadIdx.x;
    if (q >= nf4) return;
    float4 v = ((const float4*)src)[q];
    ushort4 o = make_ushort4(f2bf(v.x), f2bf(v.y), f2bf(v.z), f2bf(v.w));
    *(ushort4*)(dst + (size_t)q * 4) = o;
}

// ---------------------------------------------------------------------------
// Kernel 3a (both passes): gather event inputs (via prev indirection) into
// dense Xu/Xv fp32 [NP64,128] (for combine) + Xub/Xvb bf16 (for MFMA).
// ---------------------------------------------------------------------------
__global__ __launch_bounds__(256) void gatherx_kernel(
    const float* __restrict__ U0, const float* __restrict__ V0,
    const int* __restrict__ uids, const int* __restrict__ iids,
    const int* __restrict__ prevu, const int* __restrict__ previ,
    const float* __restrict__ NU, const float* __restrict__ NV,
    const int* __restrict__ order, const int* __restrict__ cnt_p,
    float* __restrict__ Xu, float* __restrict__ Xv,
    unsigned short* __restrict__ Xub, unsigned short* __restrict__ Xvb)
{
    int cnt = *cnt_p;
    int NP64 = (cnt + 63) & ~63;
    int sub = threadIdx.x >> 5;
    int lane = threadIdx.x & 31;
    int e = blockIdx.x * 8 + sub;
    if (e >= NP64) return;
    float4 a, c;
    if (e < cnt) {
        int t = order[e];
        int pu = prevu[t], pi = previ[t];
        const float4* up = (const float4*)(pu < 0 ?
            U0 + (size_t)uids[t] * EMB : NU + (size_t)pu * EMB);
        const float4* vp = (const float4*)(pi < 0 ?
            V0 + (size_t)iids[t] * EMB : NV + (size_t)pi * EMB);
        a = up[lane];
        c = vp[lane];
    } else {
        a = make_float4(0.f, 0.f, 0.f, 0.f);
        c = a;
    }
    ((float4*)(Xu + (size_t)e * EMB))[lane] = a;
    ((float4*)(Xv + (size_t)e * EMB))[lane] = c;
    *(ushort4*)(Xub + (size_t)e * EMB + lane * 4) =
        make_ushort4(f2bf(a.x), f2bf(a.y), f2bf(a.z), f2bf(a.w));
    *(ushort4*)(Xvb + (size_t)e * EMB + lane * 4) =
        make_ushort4(f2bf(c.x), f2bf(c.y), f2bf(c.z), f2bf(c.w));
}

// ---------------------------------------------------------------------------
// Kernel 3b (both passes): gate GEMM on MATRIX CORES (bf16 in, fp32 acc).
// G_u = Xu @ [Wuh;Wii]^T, G_v = Xv @ [Wui;Wih]^T.
// Block = 4 waves; wave w owns events e0+w*16, 4 n-tiles of 16 rows.
// mfma_f32_16x16x32_bf16: A[l&15][(l>>4)*8+i], B[(l>>4)*8+i][l&15] (both
// K-contiguous loads since G=X*W^T), D row=(l>>4)*4+reg, col=l&15 (m89).
// ---------------------------------------------------------------------------
__global__ __launch_bounds__(256) void gate_mfma_kernel(
    const unsigned short* __restrict__ Xub, const unsigned short* __restrict__ Xvb,
    const unsigned short* __restrict__ wb_uh, const unsigned short* __restrict__ wb_ii,
    const unsigned short* __restrict__ wb_ui, const unsigned short* __restrict__ wb_ih,
    const int* __restrict__ cnt_p,
    float* __restrict__ Gu, float* __restrict__ Gv)
{
    int cnt = *cnt_p;
    int NP64 = (cnt + 63) & ~63;
    int ev0 = blockIdx.x * 64;
    if (ev0 >= NP64) return;
    int z = blockIdx.z;
    int j = blockIdx.y;
    const unsigned short* X  = z ? Xvb : Xub;
    const unsigned short* W1 = z ? wb_ui : wb_uh;
    const unsigned short* W2 = z ? wb_ih : wb_ii;
    float* G = z ? Gv : Gu;
    const unsigned short* Wsrc = (j < 6) ? W1 : W2;
    int row0 = ((j < 6) ? j : j - 6) * 64;

    int tid = threadIdx.x;
    int w = tid >> 6, l = tid & 63;
    int lr = l & 15, lk = (l >> 4) * 8;

    const unsigned short* xp = X + (size_t)(ev0 + w * 16 + lr) * EMB + lk;
    const unsigned short* wp = Wsrc + (size_t)(row0 + lr) * EMB + lk;

    f32x4 acc[4] = {};
    #pragma unroll
    for (int kk = 0; kk < 4; ++kk) {
        bf16x8 a = *(const bf16x8*)(xp + kk * 32);
        #pragma unroll
        for (int n = 0; n < 4; ++n) {
            bf16x8 b = *(const bf16x8*)(wp + (size_t)n * 16 * EMB + kk * 32);
            acc[n] = __builtin_amdgcn_mfma_f32_16x16x32_bf16(a, b, acc[n], 0, 0, 0);
        }
    }
    int drow = ev0 + w * 16 + (l >> 4) * 4;
    int col = j * 64 + lr;
    #pragma unroll
    for (int n = 0; n < 4; ++n) {
        #pragma unroll
        for (int i = 0; i < 4; ++i)
            G[(size_t)(drow + i) * 768 + col + n * 16] = acc[n][i];
    }
}

// ---------------------------------------------------------------------------
// Kernel 3c (both passes): gate combine -> NU/NV (fp32 X for the z*h term).
// ---------------------------------------------------------------------------
__global__ __launch_bounds__(256) void combine_kernel(
    const float* __restrict__ Gu, const float* __restrict__ Gv,
    const float* __restrict__ Xu, const float* __restrict__ Xv,
    const float* __restrict__ bui, const float* __restrict__ buh,
    const float* __restrict__ bii, const float* __restrict__ bih,
    const int* __restrict__ order, const int* __restrict__ cnt_p,
    float* __restrict__ NU, float* __restrict__ NV)
{
    int cnt = *cnt_p;
    int e = blockIdx.x * 2 + (threadIdx.x >> 7);
    int rr = threadIdx.x & 127;
    if (e >= cnt) return;
    int t = order[e];
    const float* gu = Gu + (size_t)e * 768;
    const float* gv = Gv + (size_t)e * 768;
    float r = sigmoidf_(gv[rr] + bui[rr] + gu[rr] + buh[rr]);
    float zg = sigmoidf_(gv[128 + rr] + bui[128 + rr] + gu[128 + rr] + buh[128 + rr]);
    float n = tanhf(gv[256 + rr] + bui[256 + rr] + r * (gu[256 + rr] + buh[256 + rr]));
    float u = Xu[(size_t)e * EMB + rr];
    NU[(size_t)t * EMB + rr] = (1.f - zg) * n + zg * u;
    float r2 = sigmoidf_(gu[384 + rr] + bii[rr] + gv[384 + rr] + bih[rr]);
    float z2 = sigmoidf_(gu[512 + rr] + bii[128 + rr] + gv[512 + rr] + bih[128 + rr]);
    float n2 = tanhf(gu[640 + rr] + bii[256 + rr] + r2 * (gv[640 + rr] + bih[256 + rr]));
    float v = Xv[(size_t)e * EMB + rr];
    NV[(size_t)t * EMB + rr] = (1.f - z2) * n2 + z2 * v;
}

// ---------------------------------------------------------------------------
// Kernel 4: lev>=2 events (~15), fp32, component-serial, 1024 threads.
// #pragma unroll 1 on the batch loop is LOAD-BEARING (rounds 5/6: full unroll
// -> 768 live regs -> scratch spill -> 100% spill-BW-bound).
// ---------------------------------------------------------------------------
__global__ __launch_bounds__(1024) void tail2_kernel(
    const float* __restrict__ U0,  const float* __restrict__ V0,
    const float* __restrict__ Wui, const float* __restrict__ Wuh,
    const float* __restrict__ bui, const float* __restrict__ buh,
    const float* __restrict__ Wii, const float* __restrict__ Wih,
    const float* __restrict__ bii, const float* __restrict__ bih,
    const int* __restrict__ uids,  const int* __restrict__ iids,
    const int* __restrict__ prevu, const int* __restrict__ previ,
    const int* __restrict__ tail2Order, const int* __restrict__ compStart,
    const Hdr* __restrict__ hdr,
    float* __restrict__ NU, float* __restrict__ NV)
{
    __shared__ __align__(16) float su[EMB];
    __shared__ __align__(16) float sv[EMB];
    __shared__ float gg[1536];
    int tid = threadIdx.x;
    int ncomp = hdr->ncomp2;

    int g = tid >> 4, j = tid & 15;
    int mat = g >> 4;
    const float* W = (mat == 0) ? Wui : (mat == 1) ? Wuh : (mat == 2) ? Wii : Wih;

    for (int c = blockIdx.x; c < ncomp; c += gridDim.x) {
        int kb = compStart[c], ke = compStart[c + 1];
        for (int k = kb; k < ke; ++k) {
            int t = tail2Order[k];
            int pu = prevu[t], pi = previ[t];
            const float* up = (pu < 0) ? U0 + (size_t)uids[t] * EMB : NU + (size_t)pu * EMB;
            const float* vp = (pi < 0) ? V0 + (size_t)iids[t] * EMB : NV + (size_t)pi * EMB;
            __syncthreads();
            if (tid < EMB)        su[tid] = up[tid];
            else if (tid < 2*EMB) sv[tid - EMB] = vp[tid - EMB];
            __syncthreads();

            const float* x = (mat == 1 || mat == 2) ? su : sv;
            const float4* x4 = (const float4*)x;
            float4 xa = x4[2 * j], xb = x4[2 * j + 1];
            #pragma unroll 1
            for (int b = 0; b < 3; ++b) {
                int rbase = (g & 15) * 24 + b * 8;
                float4 w0[8], w1[8];
                #pragma unroll
                for (int q = 0; q < 8; ++q) {
                    const float4* W4 = (const float4*)(W + (size_t)(rbase + q) * EMB);
                    w0[q] = W4[2 * j]; w1[q] = W4[2 * j + 1];
                }
                #pragma unroll
                for (int q = 0; q < 8; ++q) {
                    float s = w0[q].x * xa.x + w0[q].y * xa.y
                            + w0[q].z * xa.z + w0[q].w * xa.w
                            + w1[q].x * xb.x + w1[q].y * xb.y
                            + w1[q].z * xb.z + w1[q].w * xb.w;
                    s += __shfl_xor(s, 1); s += __shfl_xor(s, 2);
                    s += __shfl_xor(s, 4); s += __shfl_xor(s, 8);
                    if (j == q) gg[mat * 384 + rbase + q] = s;
                }
            }
            __syncthreads();

            if (tid < EMB) {
                int e = tid;
                float r_ = sigmoidf_(gg[e] + bui[e] + gg[384 + e] + buh[e]);
                float z_ = sigmoidf_(gg[128 + e] + bui[128 + e] + gg[512 + e] + buh[128 + e]);
                float n_ = tanhf(gg[256 + e] + bui[256 + e] + r_ * (gg[640 + e] + buh[256 + e]));
                NU[(size_t)t * EMB + e] = (1.f - z_) * n_ + z_ * su[e];
            } else if (tid < 2*EMB) {
                int e = tid - EMB;
                float r_ = sigmoidf_(gg[768 + e] + bii[e] + gg[1152 + e] + bih[e]);
                float z_ = sigmoidf_(gg[896 + e] + bii[128 + e] + gg[1280 + e] + bih[128 + e]);
                float n_ = tanhf(gg[1024 + e] + bii[256 + e] + r_ * (gg[1408 + e] + bih[256 + e]));
                NV[(size_t)t * EMB + e] = (1.f - z_) * n_ + z_ * sv[e];
            }
        }
    }
}

// ---------------------------------------------------------------------------
// Kernel 5a: gather INPUT u,v for ALL events -> bf16 XAub/XAvb + loss.
// ---------------------------------------------------------------------------
__global__ __launch_bounds__(256) void gatherall_kernel(
    const float* __restrict__ U0, const float* __restrict__ V0,
    const int* __restrict__ uids, const int* __restrict__ iids,
    const int* __restrict__ prevu, const int* __restrict__ previ,
    const float* __restrict__ NU, const float* __restrict__ NV,
    unsigned short* __restrict__ XAub, unsigned short* __restrict__ XAvb,
    float* __restrict__ out, int nev)
{
    int sub = threadIdx.x >> 5;
    int lane = threadIdx.x & 31;
    int t = blockIdx.x * 8 + sub;
    if (t >= nev) return;
    int pu = prevu[t], pi = previ[t];
    const float4* up = (const float4*)(pu < 0 ?
        U0 + (size_t)uids[t] * EMB : NU + (size_t)pu * EMB);
    const float4* vp = (const float4*)(pi < 0 ?
        V0 + (size_t)iids[t] * EMB : NV + (size_t)pi * EMB);
    float4 a = up[lane], c = vp[lane];
    *(ushort4*)(XAub + (size_t)t * EMB + lane * 4) =
        make_ushort4(f2bf(a.x), f2bf(a.y), f2bf(a.z), f2bf(a.w));
    *(ushort4*)(XAvb + (size_t)t * EMB + lane * 4) =
        make_ushort4(f2bf(c.x), f2bf(c.y), f2bf(c.z), f2bf(c.w));
    float dp = a.x * c.x + a.y * c.y + a.z * c.z + a.w * c.w;
    dp += __shfl_xor(dp, 1); dp += __shfl_xor(dp, 2);
    dp += __shfl_xor(dp, 4); dp += __shfl_xor(dp, 8);
    dp += __shfl_xor(dp, 16);
    if (lane == 0) out[2 * (size_t)t] = -logf(softplusf_(dp) + 1e-10f);
}

// ---------------------------------------------------------------------------
// Kernel 5b: T1 GEMM on matrix cores. H1 = relu([XAu|XAv] @ T1w^T + b), K=256.
// fmaxf(NaN,0)=0 guards padded rows (poisoned XA beyond nev).
// ---------------------------------------------------------------------------
__global__ __launch_bounds__(256) void t1_mfma_kernel(
    const unsigned short* __restrict__ XAub, const unsigned short* __restrict__ XAvb,
    const unsigned short* __restrict__ t1wb, const float* __restrict__ T1b,
    float* __restrict__ H1, int nev)
{
    int ev0 = blockIdx.x * 64;
    int row0 = blockIdx.y * 64;
    int tid = threadIdx.x;
    int w = tid >> 6, l = tid & 63;
    int lr = l & 15, lk = (l >> 4) * 8;
    int erow = ev0 + w * 16 + lr;

    f32x4 acc[4] = {};
    #pragma unroll
    for (int kh = 0; kh < 8; ++kh) {
        const unsigned short* Xb = (kh < 4) ? XAub : XAvb;
        bf16x8 a = *(const bf16x8*)(Xb + (size_t)erow * EMB + (kh & 3) * 32 + lk);
        #pragma unroll
        for (int n = 0; n < 4; ++n) {
            bf16x8 b = *(const bf16x8*)(t1wb + (size_t)(row0 + n * 16 + lr) * 256 + kh * 32 + lk);
            acc[n] = __builtin_amdgcn_mfma_f32_16x16x32_bf16(a, b, acc[n], 0, 0, 0);
        }
    }
    int drow = ev0 + w * 16 + (l >> 4) * 4;
    #pragma unroll
    for (int n = 0; n < 4; ++n) {
        int col = row0 + n * 16 + lr;
        float bb = T1b[col];
        #pragma unroll
        for (int i = 0; i < 4; ++i)
            H1[(size_t)(drow + i) * EMB + col] = fmaxf(acc[n][i] + bb, 0.f);
    }
}

// ---------------------------------------------------------------------------
// Kernel 5c: T2 + T3 + sigmoid. 16 events per block; T2w staged in LDS.
// ---------------------------------------------------------------------------
__global__ __launch_bounds__(256) void t2t3_kernel(
    const float* __restrict__ H1,
    const float* __restrict__ T2w, const float* __restrict__ T2b,
    const float* __restrict__ T3w, const float* __restrict__ T3b,
    float* __restrict__ out, int nev)
{
    __shared__ __align__(16) float w2s[32][132];
    __shared__ __align__(16) float h1s[16][132];
    __shared__ float h2s[16][36];
    int tid = threadIdx.x;
    int ev = tid >> 4, j = tid & 15;
    int t = blockIdx.x * 16 + ev;

    {
        const float4* s2 = (const float4*)T2w;
        #pragma unroll
        for (int i = 0; i < 4; ++i) {
            int q = i * 256 + tid;
            int r = q >> 5, c4 = q & 31;
            *(float4*)&w2s[r][c4 * 4] = s2[q];
        }
    }
    {
        const float4* h4 = (const float4*)(H1 + (size_t)(blockIdx.x * 16 + ev) * EMB);
        *(float4*)&h1s[ev][8 * j]     = h4[2 * j];
        *(float4*)&h1s[ev][8 * j + 4] = h4[2 * j + 1];
    }
    __syncthreads();

    float acc0 = T2b[2 * j], acc1 = T2b[2 * j + 1];
    const float4* wr0 = (const float4*)&w2s[2 * j][0];
    const float4* wr1 = (const float4*)&w2s[2 * j + 1][0];
    const float4* xh = (const float4*)&h1s[ev][0];
    #pragma unroll
    for (int k = 0; k < 32; ++k) {
        float4 x = xh[k], a = wr0[k], b = wr1[k];
        acc0 = fmaf(a.x, x.x, acc0); acc0 = fmaf(a.y, x.y, acc0);
        acc0 = fmaf(a.z, x.z, acc0); acc0 = fmaf(a.w, x.w, acc0);
        acc1 = fmaf(b.x, x.x, acc1); acc1 = fmaf(b.y, x.y, acc1);
        acc1 = fmaf(b.z, x.z, acc1); acc1 = fmaf(b.w, x.w, acc1);
    }
    h2s[ev][2 * j]     = fmaxf(acc0, 0.f);
    h2s[ev][2 * j + 1] = fmaxf(acc1, 0.f);
    __syncthreads();

    float p = T3w[2 * j] * h2s[ev][2 * j] + T3w[2 * j + 1] * h2s[ev][2 * j + 1];
    p += __shfl_xor(p, 1); p += __shfl_xor(p, 2);
    p += __shfl_xor(p, 4); p += __shfl_xor(p, 8);
    if (j == 0 && t < nev)
        out[2 * (size_t)t + 1] = sigmoidf_(p + T3b[0]);
}

// ---------------------------------------------------------------------------
extern "C" void kernel_launch(void* const* d_in, const int* in_sizes, int n_in,
                              void* d_out, int out_size, void* d_ws, size_t ws_size,
                              hipStream_t stream)
{
    const float* U0  = (const float*)d_in[0];
    const float* V0  = (const float*)d_in[1];
    const float* Wui = (const float*)d_in[2];
    const float* Wuh = (const float*)d_in[3];
    const float* bui = (const float*)d_in[4];
    const float* buh = (const float*)d_in[5];
    const float* Wii = (const float*)d_in[6];
    const float* Wih = (const float*)d_in[7];
    const float* bii = (const float*)d_in[8];
    const float* bih = (const float*)d_in[9];
    const float* T1w = (const float*)d_in[10];
    const float* T1b = (const float*)d_in[11];
    const float* T2w = (const float*)d_in[12];
    const float* T2b = (const float*)d_in[13];
    const float* T3w = (const float*)d_in[14];
    const float* T3b = (const float*)d_in[15];
    const int* uids  = (const int*)d_in[16];
    const int* iids  = (const int*)d_in[17];
    int nev = in_sizes[16];

    char* ws = (char*)d_ws;
    int* base = (int*)ws;
    int* prevu      = base;                 // MAXEV
    int* previ      = base + MAXEV;         // MAXEV
    int* order0     = base + 2 * MAXEV;     // MAXEV
    int* order1     = base + 3 * MAXEV;     // MAXEV
    int* tail2Order = base + 4 * MAXEV;     // MAXEV
    int* compStart  = base + 5 * MAXEV;     // MAXEV+2
    Hdr* hdr        = (Hdr*)(base + 6 * MAXEV + 4);
    float* NU = (float*)(ws + (160 << 10));            // 2 MB
    float* NV = NU + (size_t)MAXEV * EMB;              // 2 MB
    float* Xu = NV + (size_t)MAXEV * EMB;              // 2 MB
    float* Xv = Xu + (size_t)MAXEV * EMB;              // 2 MB
    float* Gu = Xv + (size_t)MAXEV * EMB;              // 12.6 MB (reused as H1)
    float* Gv = Gu + (size_t)MAXEV * 768;              // 12.6 MB
    unsigned short* Xub = (unsigned short*)(Gv + (size_t)MAXEV * 768);  // 1 MB
    unsigned short* Xvb = Xub + (size_t)MAXEV * EMB;                    // 1 MB
    unsigned short* wb_uh = Xvb + (size_t)MAXEV * EMB;   // 96 KB each
    unsigned short* wb_ii = wb_uh + 384 * EMB;
    unsigned short* wb_ui = wb_ii + 384 * EMB;
    unsigned short* wb_ih = wb_ui + 384 * EMB;
    unsigned short* t1wb  = wb_ih + 384 * EMB;           // 64 KB
    float* out = (float*)d_out;

    prev_kernel<<<nev, 64, 0, stream>>>(uids, iids, prevu, previ, nev);
    wcvt_kernel<<<dim3(48, 5), 256, 0, stream>>>(
        Wuh, Wii, Wui, Wih, T1w, wb_uh, wb_ii, wb_ui, wb_ih, t1wb);
    setup_kernel<<<1, 1024, 0, stream>>>(prevu, previ, order0, order1,
                                         tail2Order, compStart, hdr, nev);

    // Pass A: level-0 events
    gatherx_kernel<<<(MAXEV + 7) / 8, 256, 0, stream>>>(
        U0, V0, uids, iids, prevu, previ, NU, NV, order0, &hdr->nl0,
        Xu, Xv, Xub, Xvb);
    gate_mfma_kernel<<<dim3(MAXEV / 64, 12, 2), 256, 0, stream>>>(
        Xub, Xvb, wb_uh, wb_ii, wb_ui, wb_ih, &hdr->nl0, Gu, Gv);
    combine_kernel<<<(MAXEV + 1) / 2, 256, 0, stream>>>(
        Gu, Gv, Xu, Xv, bui, buh, bii, bih, order0, &hdr->nl0, NU, NV);

    // Pass B: level-1 events
    gatherx_kernel<<<(MAXEV + 7) / 8, 256, 0, stream>>>(
        U0, V0, uids, iids, prevu, previ, NU, NV, order1, &hdr->nl1,
        Xu, Xv, Xub, Xvb);
    gate_mfma_kernel<<<dim3(MAXEV / 64, 12, 2), 256, 0, stream>>>(
        Xub, Xvb, wb_uh, wb_ii, wb_ui, wb_ih, &hdr->nl1, Gu, Gv);
    combine_kernel<<<(MAXEV + 1) / 2, 256, 0, stream>>>(
        Gu, Gv, Xu, Xv, bui, buh, bii, bih, order1, &hdr->nl1, NU, NV);

    // lev>=2 remainder: component-serial
    tail2_kernel<<<64, 1024, 0, stream>>>(
        U0, V0, Wui, Wuh, bui, buh, Wii, Wih, bii, bih,
        uids, iids, prevu, previ, tail2Order, compStart, hdr, NU, NV);

    unsigned short* XAub = Xub;   // reuse (gate passes done)
    unsigned short* XAvb = Xvb;
    float* H1 = Gu;
    gatherall_kernel<<<(nev + 7) / 8, 256, 0, stream>>>(
        U0, V0, uids, iids, prevu, previ, NU, NV, XAub, XAvb, out, nev);
    t1_mfma_kernel<<<dim3((nev + 63) / 64, 2), 256, 0, stream>>>(
        XAub, XAvb, t1wb, T1b, H1, nev);
    t2t3_kernel<<<(nev + 15) / 16, 256, 0, stream>>>(
        H1, T2w, T2b, T3w, T3b, out, nev);
}

// Round 11
// 122.593 us; speedup vs baseline: 2.0144x; 1.0370x over previous
//
#include <hip/hip_runtime.h>
#include <math.h>

#define EMB 128
#define MAXEV 4096
#define GEV 16            // events per fused-GRU block

struct Hdr { int nl0; int nl1; int ncomp2; };

typedef __attribute__((ext_vector_type(8))) short bf16x8;
typedef __attribute__((ext_vector_type(4))) float f32x4;

__device__ __forceinline__ float sigmoidf_(float x) { return 1.0f / (1.0f + expf(-x)); }
__device__ __forceinline__ float softplusf_(float x) {
    return (x > 0.f) ? x + log1pf(expf(-x)) : log1pf(expf(x));
}
__device__ __forceinline__ unsigned short f2bf(float f) {
    unsigned int u = __float_as_uint(f);
    u += 0x7FFFu + ((u >> 16) & 1u);          // round-to-nearest-even
    return (unsigned short)(u >> 16);
}
__device__ __forceinline__ float bf2f(unsigned short s) {
    return __uint_as_float((unsigned int)s << 16);
}

// ---------------------------------------------------------------------------
// Kernel 1: most recent earlier event with same user / item id.
// ---------------------------------------------------------------------------
__global__ __launch_bounds__(64) void prev_kernel(
    const int* __restrict__ uids, const int* __restrict__ iids,
    int* __restrict__ prevu, int* __restrict__ previ, int nev)
{
    int t = blockIdx.x;
    if (t >= nev) return;
    int lane = threadIdx.x;
    int myu = uids[t], myi = iids[t];
    int bu = -1, bi = -1;
    for (int j = lane; j < t; j += 64) {
        if (uids[j] == myu) bu = j;
        if (iids[j] == myi) bi = j;
    }
    for (int off = 32; off; off >>= 1) {
        bu = max(bu, __shfl_xor(bu, off));
        bi = max(bi, __shfl_xor(bi, off));
    }
    if (lane == 0) { prevu[t] = bu; previ[t] = bi; }
}

// ---------------------------------------------------------------------------
// Kernel 2 (single block): exact DAG levels, partition lev0/lev1/lev>=2;
// lev>=2 grouped by connected component and sorted by (comp, t).
// ---------------------------------------------------------------------------
__global__ __launch_bounds__(1024) void setup_kernel(
    const int* __restrict__ prevu, const int* __restrict__ previ,
    int* __restrict__ order0, int* __restrict__ order1,
    int* __restrict__ tail2Order, int* __restrict__ compStart,
    Hdr* __restrict__ hdr, int nev)
{
    __shared__ int   lab[MAXEV];
    __shared__ int   tmpT[MAXEV];
    __shared__ int   skey[MAXEV];
    __shared__ short slev[MAXEV];
    __shared__ int   schanged, sn0, sn1, sn2;

    int tid = threadIdx.x;
    for (int t = tid; t < nev; t += 1024) { lab[t] = t; slev[t] = 0; }
    if (tid == 0) { sn0 = 0; sn1 = 0; sn2 = 0; }
    __syncthreads();

    for (int it = 0; it < nev; ++it) {
        if (tid == 0) schanged = 0;
        __syncthreads();
        for (int t = tid; t < nev; t += 1024) {
            int pu = prevu[t], pi = previ[t];
            int nl = 0;
            if (pu >= 0) nl = slev[pu] + 1;
            if (pi >= 0) { int c = slev[pi] + 1; nl = nl > c ? nl : c; }
            if (nl > (int)slev[t]) { slev[t] = (short)nl; schanged = 1; }
        }
        __syncthreads();
        if (!schanged) break;
        __syncthreads();
    }

    for (int it = 0; it < nev; ++it) {
        if (tid == 0) schanged = 0;
        __syncthreads();
        for (int t = tid; t < nev; t += 1024) {
            int m = lab[t];
            int pu = prevu[t], pi = previ[t];
            if (pu >= 0) m = min(m, lab[pu]);
            if (pi >= 0) m = min(m, lab[pi]);
            if (m < lab[t]) { atomicMin(&lab[t], m); schanged = 1; }
            if (pu >= 0 && m < lab[pu]) { atomicMin(&lab[pu], m); schanged = 1; }
            if (pi >= 0 && m < lab[pi]) { atomicMin(&lab[pi], m); schanged = 1; }
        }
        __syncthreads();
        if (!schanged) break;
        __syncthreads();
    }

    for (int t = tid; t < nev; t += 1024) {
        int l = slev[t];
        if (l == 0)      order0[atomicAdd(&sn0, 1)] = t;
        else if (l == 1) order1[atomicAdd(&sn1, 1)] = t;
        else             tmpT[atomicAdd(&sn2, 1)] = t;
    }
    __syncthreads();
    int n2 = sn2;

    for (int i = tid; i < n2; i += 1024)
        skey[i] = (lab[tmpT[i]] << 12) | tmpT[i];
    __syncthreads();

    for (int i = tid; i < n2; i += 1024) {
        int k = skey[i], r = 0;
        for (int j = 0; j < n2; ++j) r += (skey[j] < k);
        tail2Order[r] = tmpT[i];
        lab[r] = k;
    }
    __syncthreads();

    if (tid == 0) {
        int nc = 0;
        for (int i = 0; i < n2; ++i)
            if (i == 0 || (lab[i] >> 12) != (lab[i - 1] >> 12))
                compStart[nc++] = i;
        compStart[nc] = n2;
        hdr->nl0 = sn0;
        hdr->nl1 = sn1;
        hdr->ncomp2 = nc;
    }
}

// ---------------------------------------------------------------------------
// Kernel 2b: convert the 4 GRU matrices + T1w to bf16 (once).
// ---------------------------------------------------------------------------
__global__ __launch_bounds__(256) void wcvt_kernel(
    const float* __restrict__ Wuh, const float* __restrict__ Wii,
    const float* __restrict__ Wui, const float* __restrict__ Wih,
    const float* __restrict__ T1w,
    unsigned short* __restrict__ wb_uh, unsigned short* __restrict__ wb_ii,
    unsigned short* __restrict__ wb_ui, unsigned short* __restrict__ wb_ih,
    unsigned short* __restrict__ t1wb)
{
    int m = blockIdx.y;
    const float* src = (m == 0) ? Wuh : (m == 1) ? Wii : (m == 2) ? Wui
                      : (m == 3) ? Wih : T1w;
    unsigned short* dst = (m == 0) ? wb_uh : (m == 1) ? wb_ii : (m == 2) ? wb_ui
                        : (m == 3) ? wb_ih : t1wb;
    int nf4 = (m < 4) ? (384 * EMB / 4) : (EMB * 256 / 4);
    int q = blockIdx.x * 256 + threadIdx.x;
    if (q >= nf4) return;
    float4 v = ((const float4*)src)[q];
    ushort4 o = make_ushort4(f2bf(v.x), f2bf(v.y), f2bf(v.z), f2bf(v.w));
    *(ushort4*)(dst + (size_t)q * 4) = o;
}

// ---------------------------------------------------------------------------
// Kernel 3 (both passes, FUSED): gather -> gate MFMA -> GRU combine.
// Block = 16 events, 256 threads (4 waves). Stage u,v as bf16 in LDS;
// two phases (user cell / item cell): 48 n-tiles of 16 gate rows, each wave
// owns 12 (acc = 12 x f32x4, static idx). B-frags straight from L2-resident
// bf16 weights. D -> gg LDS (772 pad breaks 768-stride bank alignment) ->
// combine -> NU/NV. No Gu/Gv traffic, no separate gather/combine launches.
// NUr/NVr alias NU/NV (no __restrict__): pass A never reads them; pass B
// reads only pass-A rows (cross-launch, stream-ordered).
// ---------------------------------------------------------------------------
__global__ __launch_bounds__(256) void gru_fused_kernel(
    const float* __restrict__ U0, const float* __restrict__ V0,
    const unsigned short* __restrict__ wb_ui, const unsigned short* __restrict__ wb_uh,
    const unsigned short* __restrict__ wb_ii, const unsigned short* __restrict__ wb_ih,
    const float* __restrict__ bui, const float* __restrict__ buh,
    const float* __restrict__ bii, const float* __restrict__ bih,
    const int* __restrict__ uids, const int* __restrict__ iids,
    const int* __restrict__ prevu, const int* __restrict__ previ,
    const float* NUr, const float* NVr,
    const int* __restrict__ order, const int* __restrict__ cnt_p,
    float* NU, float* NV)
{
    __shared__ __align__(16) unsigned short xbu[GEV][EMB];
    __shared__ __align__(16) unsigned short xbv[GEV][EMB];
    __shared__ float gg[GEV][772];

    int cnt = *cnt_p;
    int e0 = blockIdx.x * GEV;
    if (e0 >= cnt) return;

    int tid = threadIdx.x;
    int ev = tid >> 4, c8 = (tid & 15) * 8;

    {   // stage: 16 threads per event, 8 channels each; zero-pad beyond cnt
        int e = e0 + ev;
        float4 a0, a1, c0, c1;
        if (e < cnt) {
            int t = order[e];
            int pu = prevu[t], pi = previ[t];
            const float* up = (pu < 0 ? U0 + (size_t)uids[t] * EMB : NUr + (size_t)pu * EMB) + c8;
            const float* vp = (pi < 0 ? V0 + (size_t)iids[t] * EMB : NVr + (size_t)pi * EMB) + c8;
            a0 = ((const float4*)up)[0]; a1 = ((const float4*)up)[1];
            c0 = ((const float4*)vp)[0]; c1 = ((const float4*)vp)[1];
        } else {
            a0 = make_float4(0.f, 0.f, 0.f, 0.f); a1 = a0; c0 = a0; c1 = a0;
        }
        *(ushort4*)&xbu[ev][c8]     = make_ushort4(f2bf(a0.x), f2bf(a0.y), f2bf(a0.z), f2bf(a0.w));
        *(ushort4*)&xbu[ev][c8 + 4] = make_ushort4(f2bf(a1.x), f2bf(a1.y), f2bf(a1.z), f2bf(a1.w));
        *(ushort4*)&xbv[ev][c8]     = make_ushort4(f2bf(c0.x), f2bf(c0.y), f2bf(c0.z), f2bf(c0.w));
        *(ushort4*)&xbv[ev][c8 + 4] = make_ushort4(f2bf(c1.x), f2bf(c1.y), f2bf(c1.z), f2bf(c1.w));
    }
    __syncthreads();

    int w = tid >> 6, l = tid & 63;
    int lr = l & 15, lk = (l >> 4) * 8;

    for (int ph = 0; ph < 2; ++ph) {
        const unsigned short* Wi = ph ? wb_ii : wb_ui;   // gi matrix
        const unsigned short* Wh = ph ? wb_ih : wb_uh;   // gh matrix
        const unsigned short (*Xi)[EMB] = ph ? xbu : xbv;   // gi input (x)
        const unsigned short (*Xh)[EMB] = ph ? xbv : xbu;   // gh input (h)

        f32x4 acc[12] = {};
        #pragma unroll
        for (int kk = 0; kk < 4; ++kk) {
            bf16x8 ai = *(const bf16x8*)&Xi[lr][kk * 32 + lk];
            bf16x8 ah = *(const bf16x8*)&Xh[lr][kk * 32 + lk];
            #pragma unroll
            for (int j = 0; j < 12; ++j) {
                int nt = w * 12 + j;
                bool ish = nt >= 24;
                int brow = (ish ? nt - 24 : nt) * 16 + lr;
                const unsigned short* W = ish ? Wh : Wi;
                bf16x8 b = *(const bf16x8*)(W + (size_t)brow * EMB + kk * 32 + lk);
                acc[j] = __builtin_amdgcn_mfma_f32_16x16x32_bf16(ish ? ah : ai, b, acc[j], 0, 0, 0);
            }
        }
        #pragma unroll
        for (int j = 0; j < 12; ++j) {
            int nt = w * 12 + j;
            #pragma unroll
            for (int i = 0; i < 4; ++i)
                gg[(l >> 4) * 4 + i][nt * 16 + lr] = acc[j][i];
        }
        __syncthreads();

        {   // combine (gg[ev][0..383]=gi, [384..767]=gh)
            int e = e0 + ev;
            if (e < cnt) {
                int t = order[e];
                const float* bi = ph ? bii : bui;
                const float* bh = ph ? bih : buh;
                float* N = ph ? NV : NU;
                const unsigned short (*xh)[EMB] = ph ? xbv : xbu;
                #pragma unroll
                for (int i = 0; i < 8; ++i) {
                    int ch = c8 + i;
                    float r_ = sigmoidf_(gg[ev][ch] + bi[ch] + gg[ev][384 + ch] + bh[ch]);
                    float z_ = sigmoidf_(gg[ev][128 + ch] + bi[128 + ch] + gg[ev][512 + ch] + bh[128 + ch]);
                    float n_ = tanhf(gg[ev][256 + ch] + bi[256 + ch] + r_ * (gg[ev][640 + ch] + bh[256 + ch]));
                    float h = bf2f(xh[ev][ch]);
                    N[(size_t)t * EMB + ch] = (1.f - z_) * n_ + z_ * h;
                }
            }
        }
        __syncthreads();   // gg/acc reuse in next phase
    }
}

// ---------------------------------------------------------------------------
// Kernel 4: lev>=2 events (~15), fp32, component-serial, 1024 threads.
// #pragma unroll 1 on the batch loop is LOAD-BEARING (rounds 5/6: full unroll
// -> 768 live regs -> scratch spill -> 100% spill-BW-bound).
// ---------------------------------------------------------------------------
__global__ __launch_bounds__(1024) void tail2_kernel(
    const float* __restrict__ U0,  const float* __restrict__ V0,
    const float* __restrict__ Wui, const float* __restrict__ Wuh,
    const float* __restrict__ bui, const float* __restrict__ buh,
    const float* __restrict__ Wii, const float* __restrict__ Wih,
    const float* __restrict__ bii, const float* __restrict__ bih,
    const int* __restrict__ uids,  const int* __restrict__ iids,
    const int* __restrict__ prevu, const int* __restrict__ previ,
    const int* __restrict__ tail2Order, const int* __restrict__ compStart,
    const Hdr* __restrict__ hdr,
    float* __restrict__ NU, float* __restrict__ NV)
{
    __shared__ __align__(16) float su[EMB];
    __shared__ __align__(16) float sv[EMB];
    __shared__ float gg[1536];
    int tid = threadIdx.x;
    int ncomp = hdr->ncomp2;

    int g = tid >> 4, j = tid & 15;
    int mat = g >> 4;
    const float* W = (mat == 0) ? Wui : (mat == 1) ? Wuh : (mat == 2) ? Wii : Wih;

    for (int c = blockIdx.x; c < ncomp; c += gridDim.x) {
        int kb = compStart[c], ke = compStart[c + 1];
        for (int k = kb; k < ke; ++k) {
            int t = tail2Order[k];
            int pu = prevu[t], pi = previ[t];
            const float* up = (pu < 0) ? U0 + (size_t)uids[t] * EMB : NU + (size_t)pu * EMB;
            const float* vp = (pi < 0) ? V0 + (size_t)iids[t] * EMB : NV + (size_t)pi * EMB;
            __syncthreads();
            if (tid < EMB)        su[tid] = up[tid];
            else if (tid < 2*EMB) sv[tid - EMB] = vp[tid - EMB];
            __syncthreads();

            const float* x = (mat == 1 || mat == 2) ? su : sv;
            const float4* x4 = (const float4*)x;
            float4 xa = x4[2 * j], xb = x4[2 * j + 1];
            #pragma unroll 1
            for (int b = 0; b < 3; ++b) {
                int rbase = (g & 15) * 24 + b * 8;
                float4 w0[8], w1[8];
                #pragma unroll
                for (int q = 0; q < 8; ++q) {
                    const float4* W4 = (const float4*)(W + (size_t)(rbase + q) * EMB);
                    w0[q] = W4[2 * j]; w1[q] = W4[2 * j + 1];
                }
                #pragma unroll
                for (int q = 0; q < 8; ++q) {
                    float s = w0[q].x * xa.x + w0[q].y * xa.y
                            + w0[q].z * xa.z + w0[q].w * xa.w
                            + w1[q].x * xb.x + w1[q].y * xb.y
                            + w1[q].z * xb.z + w1[q].w * xb.w;
                    s += __shfl_xor(s, 1); s += __shfl_xor(s, 2);
                    s += __shfl_xor(s, 4); s += __shfl_xor(s, 8);
                    if (j == q) gg[mat * 384 + rbase + q] = s;
                }
            }
            __syncthreads();

            if (tid < EMB) {
                int e = tid;
                float r_ = sigmoidf_(gg[e] + bui[e] + gg[384 + e] + buh[e]);
                float z_ = sigmoidf_(gg[128 + e] + bui[128 + e] + gg[512 + e] + buh[128 + e]);
                float n_ = tanhf(gg[256 + e] + bui[256 + e] + r_ * (gg[640 + e] + buh[256 + e]));
                NU[(size_t)t * EMB + e] = (1.f - z_) * n_ + z_ * su[e];
            } else if (tid < 2*EMB) {
                int e = tid - EMB;
                float r_ = sigmoidf_(gg[768 + e] + bii[e] + gg[1152 + e] + bih[e]);
                float z_ = sigmoidf_(gg[896 + e] + bii[128 + e] + gg[1280 + e] + bih[128 + e]);
                float n_ = tanhf(gg[1024 + e] + bii[256 + e] + r_ * (gg[1408 + e] + bih[256 + e]));
                NV[(size_t)t * EMB + e] = (1.f - z_) * n_ + z_ * sv[e];
            }
        }
    }
}

// ---------------------------------------------------------------------------
// Kernel 5a: gather INPUT u,v for ALL events -> bf16 XAub/XAvb + loss.
// ---------------------------------------------------------------------------
__global__ __launch_bounds__(256) void gatherall_kernel(
    const float* __restrict__ U0, const float* __restrict__ V0,
    const int* __restrict__ uids, const int* __restrict__ iids,
    const int* __restrict__ prevu, const int* __restrict__ previ,
    const float* __restrict__ NU, const float* __restrict__ NV,
    unsigned short* __restrict__ XAub, unsigned short* __restrict__ XAvb,
    float* __restrict__ out, int nev)
{
    int sub = threadIdx.x >> 5;
    int lane = threadIdx.x & 31;
    int t = blockIdx.x * 8 + sub;
    if (t >= nev) return;
    int pu = prevu[t], pi = previ[t];
    const float4* up = (const float4*)(pu < 0 ?
        U0 + (size_t)uids[t] * EMB : NU + (size_t)pu * EMB);
    const float4* vp = (const float4*)(pi < 0 ?
        V0 + (size_t)iids[t] * EMB : NV + (size_t)pi * EMB);
    float4 a = up[lane], c = vp[lane];
    *(ushort4*)(XAub + (size_t)t * EMB + lane * 4) =
        make_ushort4(f2bf(a.x), f2bf(a.y), f2bf(a.z), f2bf(a.w));
    *(ushort4*)(XAvb + (size_t)t * EMB + lane * 4) =
        make_ushort4(f2bf(c.x), f2bf(c.y), f2bf(c.z), f2bf(c.w));
    float dp = a.x * c.x + a.y * c.y + a.z * c.z + a.w * c.w;
    dp += __shfl_xor(dp, 1); dp += __shfl_xor(dp, 2);
    dp += __shfl_xor(dp, 4); dp += __shfl_xor(dp, 8);
    dp += __shfl_xor(dp, 16);
    if (lane == 0) out[2 * (size_t)t] = -logf(softplusf_(dp) + 1e-10f);
}

// ---------------------------------------------------------------------------
// Kernel 5b: T1 GEMM on matrix cores. H1 = relu([XAu|XAv] @ T1w^T + b), K=256.
// fmaxf(NaN,0)=0 guards padded rows (poisoned XA beyond nev).
// ---------------------------------------------------------------------------
__global__ __launch_bounds__(256) void t1_mfma_kernel(
    const unsigned short* __restrict__ XAub, const unsigned short* __restrict__ XAvb,
    const unsigned short* __restrict__ t1wb, const float* __restrict__ T1b,
    float* __restrict__ H1, int nev)
{
    int ev0 = blockIdx.x * 64;
    int row0 = blockIdx.y * 64;
    int tid = threadIdx.x;
    int w = tid >> 6, l = tid & 63;
    int lr = l & 15, lk = (l >> 4) * 8;
    int erow = ev0 + w * 16 + lr;

    f32x4 acc[4] = {};
    #pragma unroll
    for (int kh = 0; kh < 8; ++kh) {
        const unsigned short* Xb = (kh < 4) ? XAub : XAvb;
        bf16x8 a = *(const bf16x8*)(Xb + (size_t)erow * EMB + (kh & 3) * 32 + lk);
        #pragma unroll
        for (int n = 0; n < 4; ++n) {
            bf16x8 b = *(const bf16x8*)(t1wb + (size_t)(row0 + n * 16 + lr) * 256 + kh * 32 + lk);
            acc[n] = __builtin_amdgcn_mfma_f32_16x16x32_bf16(a, b, acc[n], 0, 0, 0);
        }
    }
    int drow = ev0 + w * 16 + (l >> 4) * 4;
    #pragma unroll
    for (int n = 0; n < 4; ++n) {
        int col = row0 + n * 16 + lr;
        float bb = T1b[col];
        #pragma unroll
        for (int i = 0; i < 4; ++i)
            H1[(size_t)(drow + i) * EMB + col] = fmaxf(acc[n][i] + bb, 0.f);
    }
}

// ---------------------------------------------------------------------------
// Kernel 5c: T2 + T3 + sigmoid. 16 events per block; T2w staged in LDS.
// ---------------------------------------------------------------------------
__global__ __launch_bounds__(256) void t2t3_kernel(
    const float* __restrict__ H1,
    const float* __restrict__ T2w, const float* __restrict__ T2b,
    const float* __restrict__ T3w, const float* __restrict__ T3b,
    float* __restrict__ out, int nev)
{
    __shared__ __align__(16) float w2s[32][132];
    __shared__ __align__(16) float h1s[16][132];
    __shared__ float h2s[16][36];
    int tid = threadIdx.x;
    int ev = tid >> 4, j = tid & 15;
    int t = blockIdx.x * 16 + ev;

    {
        const float4* s2 = (const float4*)T2w;
        #pragma unroll
        for (int i = 0; i < 4; ++i) {
            int q = i * 256 + tid;
            int r = q >> 5, c4 = q & 31;
            *(float4*)&w2s[r][c4 * 4] = s2[q];
        }
    }
    {
        const float4* h4 = (const float4*)(H1 + (size_t)(blockIdx.x * 16 + ev) * EMB);
        *(float4*)&h1s[ev][8 * j]     = h4[2 * j];
        *(float4*)&h1s[ev][8 * j + 4] = h4[2 * j + 1];
    }
    __syncthreads();

    float acc0 = T2b[2 * j], acc1 = T2b[2 * j + 1];
    const float4* wr0 = (const float4*)&w2s[2 * j][0];
    const float4* wr1 = (const float4*)&w2s[2 * j + 1][0];
    const float4* xh = (const float4*)&h1s[ev][0];
    #pragma unroll
    for (int k = 0; k < 32; ++k) {
        float4 x = xh[k], a = wr0[k], b = wr1[k];
        acc0 = fmaf(a.x, x.x, acc0); acc0 = fmaf(a.y, x.y, acc0);
        acc0 = fmaf(a.z, x.z, acc0); acc0 = fmaf(a.w, x.w, acc0);
        acc1 = fmaf(b.x, x.x, acc1); acc1 = fmaf(b.y, x.y, acc1);
        acc1 = fmaf(b.z, x.z, acc1); acc1 = fmaf(b.w, x.w, acc1);
    }
    h2s[ev][2 * j]     = fmaxf(acc0, 0.f);
    h2s[ev][2 * j + 1] = fmaxf(acc1, 0.f);
    __syncthreads();

    float p = T3w[2 * j] * h2s[ev][2 * j] + T3w[2 * j + 1] * h2s[ev][2 * j + 1];
    p += __shfl_xor(p, 1); p += __shfl_xor(p, 2);
    p += __shfl_xor(p, 4); p += __shfl_xor(p, 8);
    if (j == 0 && t < nev)
        out[2 * (size_t)t + 1] = sigmoidf_(p + T3b[0]);
}

// ---------------------------------------------------------------------------
extern "C" void kernel_launch(void* const* d_in, const int* in_sizes, int n_in,
                              void* d_out, int out_size, void* d_ws, size_t ws_size,
                              hipStream_t stream)
{
    const float* U0  = (const float*)d_in[0];
    const float* V0  = (const float*)d_in[1];
    const float* Wui = (const float*)d_in[2];
    const float* Wuh = (const float*)d_in[3];
    const float* bui = (const float*)d_in[4];
    const float* buh = (const float*)d_in[5];
    const float* Wii = (const float*)d_in[6];
    const float* Wih = (const float*)d_in[7];
    const float* bii = (const float*)d_in[8];
    const float* bih = (const float*)d_in[9];
    const float* T1w = (const float*)d_in[10];
    const float* T1b = (const float*)d_in[11];
    const float* T2w = (const float*)d_in[12];
    const float* T2b = (const float*)d_in[13];
    const float* T3w = (const float*)d_in[14];
    const float* T3b = (const float*)d_in[15];
    const int* uids  = (const int*)d_in[16];
    const int* iids  = (const int*)d_in[17];
    int nev = in_sizes[16];

    char* ws = (char*)d_ws;
    int* base = (int*)ws;
    int* prevu      = base;                 // MAXEV
    int* previ      = base + MAXEV;         // MAXEV
    int* order0     = base + 2 * MAXEV;     // MAXEV
    int* order1     = base + 3 * MAXEV;     // MAXEV
    int* tail2Order = base + 4 * MAXEV;     // MAXEV
    int* compStart  = base + 5 * MAXEV;     // MAXEV+2
    Hdr* hdr        = (Hdr*)(base + 6 * MAXEV + 4);
    float* NU = (float*)(ws + (160 << 10));            // 2 MB
    float* NV = NU + (size_t)MAXEV * EMB;              // 2 MB
    float* Xu = NV + (size_t)MAXEV * EMB;              // (unused, layout kept)
    float* Xv = Xu + (size_t)MAXEV * EMB;
    float* Gu = Xv + (size_t)MAXEV * EMB;              // 12.6 MB (H1)
    float* Gv = Gu + (size_t)MAXEV * 768;              // 12.6 MB (unused)
    unsigned short* Xub = (unsigned short*)(Gv + (size_t)MAXEV * 768);  // 1 MB
    unsigned short* Xvb = Xub + (size_t)MAXEV * EMB;                    // 1 MB
    unsigned short* wb_uh = Xvb + (size_t)MAXEV * EMB;   // 96 KB each
    unsigned short* wb_ii = wb_uh + 384 * EMB;
    unsigned short* wb_ui = wb_ii + 384 * EMB;
    unsigned short* wb_ih = wb_ui + 384 * EMB;
    unsigned short* t1wb  = wb_ih + 384 * EMB;           // 64 KB
    float* out = (float*)d_out;

    prev_kernel<<<nev, 64, 0, stream>>>(uids, iids, prevu, previ, nev);
    wcvt_kernel<<<dim3(48, 5), 256, 0, stream>>>(
        Wuh, Wii, Wui, Wih, T1w, wb_uh, wb_ii, wb_ui, wb_ih, t1wb);
    setup_kernel<<<1, 1024, 0, stream>>>(prevu, previ, order0, order1,
                                         tail2Order, compStart, hdr, nev);

    // Pass A: level-0 events (fused gather + gate MFMA + combine)
    gru_fused_kernel<<<MAXEV / GEV, 256, 0, stream>>>(
        U0, V0, wb_ui, wb_uh, wb_ii, wb_ih, bui, buh, bii, bih,
        uids, iids, prevu, previ, NU, NV, order0, &hdr->nl0, NU, NV);

    // Pass B: level-1 events (preds all level-0, visible by stream order)
    gru_fused_kernel<<<MAXEV / GEV, 256, 0, stream>>>(
        U0, V0, wb_ui, wb_uh, wb_ii, wb_ih, bui, buh, bii, bih,
        uids, iids, prevu, previ, NU, NV, order1, &hdr->nl1, NU, NV);

    // lev>=2 remainder: component-serial
    tail2_kernel<<<64, 1024, 0, stream>>>(
        U0, V0, Wui, Wuh, bui, buh, Wii, Wih, bii, bih,
        uids, iids, prevu, previ, tail2Order, compStart, hdr, NU, NV);

    unsigned short* XAub = Xub;
    unsigned short* XAvb = Xvb;
    float* H1 = Gu;
    gatherall_kernel<<<(nev + 7) / 8, 256, 0, stream>>>(
        U0, V0, uids, iids, prevu, previ, NU, NV, XAub, XAvb, out, nev);
    t1_mfma_kernel<<<dim3((nev + 63) / 64, 2), 256, 0, stream>>>(
        XAub, XAvb, t1wb, T1b, H1, nev);
    t2t3_kernel<<<(nev + 15) / 16, 256, 0, stream>>>(
        H1, T2w, T2b, T3w, T3b, out, nev);
}

// Round 12
// 107.327 us; speedup vs baseline: 2.3009x; 1.1422x over previous
//
#include <hip/hip_runtime.h>
#include <math.h>

#define EMB 128
#define MAXEV 4096
#define GEV 16            // events per fused-GRU block

struct Hdr { int nl0; int nl1; int ncomp2; };

typedef __attribute__((ext_vector_type(8))) short bf16x8;
typedef __attribute__((ext_vector_type(4))) float f32x4;

__device__ __forceinline__ float sigmoidf_(float x) { return 1.0f / (1.0f + expf(-x)); }
__device__ __forceinline__ float softplusf_(float x) {
    return (x > 0.f) ? x + log1pf(expf(-x)) : log1pf(expf(x));
}
__device__ __forceinline__ unsigned short f2bf(float f) {
    unsigned int u = __float_as_uint(f);
    u += 0x7FFFu + ((u >> 16) & 1u);          // round-to-nearest-even
    return (unsigned short)(u >> 16);
}
__device__ __forceinline__ float bf2f(unsigned short s) {
    return __uint_as_float((unsigned int)s << 16);
}

// ---------------------------------------------------------------------------
// Kernel 1 (fused): per-event prev-id search + one-shot weight->bf16 convert.
// grid = MAXEV blocks x 64; first 58368 global threads also convert one f4.
// ---------------------------------------------------------------------------
__global__ __launch_bounds__(64) void prev_kernel(
    const int* __restrict__ uids, const int* __restrict__ iids,
    int* __restrict__ prevu, int* __restrict__ previ, int nev,
    const float* __restrict__ Wuh, const float* __restrict__ Wii,
    const float* __restrict__ Wui, const float* __restrict__ Wih,
    const float* __restrict__ T1w, const float* __restrict__ T2w,
    unsigned short* __restrict__ wb_uh, unsigned short* __restrict__ wb_ii,
    unsigned short* __restrict__ wb_ui, unsigned short* __restrict__ wb_ih,
    unsigned short* __restrict__ t1wb, unsigned short* __restrict__ t2wb)
{
    int t = blockIdx.x;
    int lane = threadIdx.x;

    {   // weight conversion: 49152 (4x GRU) + 8192 (T1w) + 1024 (T2w) f4
        int gid = t * 64 + lane;
        if (gid < 58368) {
            const float* src; unsigned short* dst; int q;
            if (gid < 49152) {
                int m = gid / 12288; q = gid - m * 12288;
                src = (m == 0) ? Wuh : (m == 1) ? Wii : (m == 2) ? Wui : Wih;
                dst = (m == 0) ? wb_uh : (m == 1) ? wb_ii : (m == 2) ? wb_ui : wb_ih;
            } else if (gid < 57344) { q = gid - 49152; src = T1w; dst = t1wb; }
            else                    { q = gid - 57344; src = T2w; dst = t2wb; }
            float4 v = ((const float4*)src)[q];
            *(ushort4*)(dst + (size_t)q * 4) =
                make_ushort4(f2bf(v.x), f2bf(v.y), f2bf(v.z), f2bf(v.w));
        }
    }

    if (t >= nev) return;
    int myu = uids[t], myi = iids[t];
    int bu = -1, bi = -1;
    for (int j = lane; j < t; j += 64) {
        if (uids[j] == myu) bu = j;
        if (iids[j] == myi) bi = j;
    }
    for (int off = 32; off; off >>= 1) {
        bu = max(bu, __shfl_xor(bu, off));
        bi = max(bi, __shfl_xor(bi, off));
    }
    if (lane == 0) { prevu[t] = bu; previ[t] = bi; }
}

// ---------------------------------------------------------------------------
// Kernel 2 (single block): levels relaxed ONLY over pred-having events
// (~250); components ONLY over the lev>=2 induced subgraph (~15 events) --
// correct because two lev>=2 events linked solely through a lev<=1 node have
// no mutual dependency (that ancestor completes in pass A/B).
// ---------------------------------------------------------------------------
__global__ __launch_bounds__(1024) void setup_kernel(
    const int* __restrict__ prevu, const int* __restrict__ previ,
    int* __restrict__ order0, int* __restrict__ order1,
    int* __restrict__ tail2Order, int* __restrict__ compStart,
    Hdr* __restrict__ hdr, int nev)
{
    __shared__ int   lab[MAXEV];     // component label, indexed by t
    __shared__ int   tmpT[MAXEV];    // pred-having events; later rank keys
    __shared__ int   t2l[MAXEV];     // lev>=2 list
    __shared__ short slev[MAXEV];
    __shared__ int   schanged, sn0, sn1, sn2, sntl;

    int tid = threadIdx.x;
    for (int t = tid; t < nev; t += 1024) slev[t] = 0;
    if (tid == 0) { sn0 = 0; sn1 = 0; sn2 = 0; sntl = 0; }
    __syncthreads();

    for (int t = tid; t < nev; t += 1024) {
        if (prevu[t] >= 0 || previ[t] >= 0) tmpT[atomicAdd(&sntl, 1)] = t;
        else                                 order0[atomicAdd(&sn0, 1)] = t;
    }
    __syncthreads();
    int ntl = sntl;

    // level relaxation over the tail-candidate list only
    for (int it = 0; it < nev; ++it) {
        if (tid == 0) schanged = 0;
        __syncthreads();
        for (int i = tid; i < ntl; i += 1024) {
            int t = tmpT[i];
            int pu = prevu[t], pi = previ[t];
            int nl = 0;
            if (pu >= 0) nl = slev[pu] + 1;
            if (pi >= 0) { int c = slev[pi] + 1; nl = nl > c ? nl : c; }
            if (nl > (int)slev[t]) { slev[t] = (short)nl; schanged = 1; }
        }
        __syncthreads();
        if (!schanged) break;
        __syncthreads();
    }

    for (int i = tid; i < ntl; i += 1024) {
        int t = tmpT[i];
        if (slev[t] == 1)      order1[atomicAdd(&sn1, 1)] = t;
        else if (slev[t] >= 2) t2l[atomicAdd(&sn2, 1)] = t;
    }
    __syncthreads();
    int n2 = sn2;

    // components over lev>=2 subgraph only
    for (int i = tid; i < n2; i += 1024) lab[t2l[i]] = t2l[i];
    __syncthreads();
    for (int it = 0; it < nev; ++it) {
        if (tid == 0) schanged = 0;
        __syncthreads();
        for (int i = tid; i < n2; i += 1024) {
            int t = t2l[i];
            int m = lab[t];
            int pu = prevu[t], pi = previ[t];
            bool eu = (pu >= 0 && slev[pu] >= 2);
            bool ei = (pi >= 0 && slev[pi] >= 2);
            if (eu) m = min(m, lab[pu]);
            if (ei) m = min(m, lab[pi]);
            if (m < lab[t]) { atomicMin(&lab[t], m); schanged = 1; }
            if (eu && m < lab[pu]) { atomicMin(&lab[pu], m); schanged = 1; }
            if (ei && m < lab[pi]) { atomicMin(&lab[pi], m); schanged = 1; }
        }
        __syncthreads();
        if (!schanged) break;
        __syncthreads();
    }

    // rank-sort lev>=2 by (lab, t); boundaries read lab[] via sorted order
    for (int i = tid; i < n2; i += 1024) tmpT[i] = (lab[t2l[i]] << 12) | t2l[i];
    __syncthreads();
    for (int i = tid; i < n2; i += 1024) {
        int k = tmpT[i], r = 0;
        for (int j = 0; j < n2; ++j) r += (tmpT[j] < k);
        tail2Order[r] = k & 0xFFF;
    }
    __syncthreads();

    if (tid == 0) {
        int nc = 0;
        for (int i = 0; i < n2; ++i)
            if (i == 0 || lab[tail2Order[i]] != lab[tail2Order[i - 1]])
                compStart[nc++] = i;
        compStart[nc] = n2;
        hdr->ncomp2 = nc;
        hdr->nl0 = sn0;
        hdr->nl1 = sn1;
    }
}

// ---------------------------------------------------------------------------
// Kernel 3 (both passes, FUSED): gather -> gate MFMA -> GRU combine.
// Block = 16 events, 4 waves. bf16 u,v staged in LDS (stride 136 shorts ->
// row step 4 banks, 2-way conflict = free; 128-stride was a 16-way).
// gg pad 772 breaks 768-stride alignment. NUr/NVr alias NU/NV (no restrict).
// ---------------------------------------------------------------------------
__global__ __launch_bounds__(256) void gru_fused_kernel(
    const float* __restrict__ U0, const float* __restrict__ V0,
    const unsigned short* __restrict__ wb_ui, const unsigned short* __restrict__ wb_uh,
    const unsigned short* __restrict__ wb_ii, const unsigned short* __restrict__ wb_ih,
    const float* __restrict__ bui, const float* __restrict__ buh,
    const float* __restrict__ bii, const float* __restrict__ bih,
    const int* __restrict__ uids, const int* __restrict__ iids,
    const int* __restrict__ prevu, const int* __restrict__ previ,
    const float* NUr, const float* NVr,
    const int* __restrict__ order, const int* __restrict__ cnt_p,
    float* NU, float* NV)
{
    __shared__ __align__(16) unsigned short xbu[GEV][136];
    __shared__ __align__(16) unsigned short xbv[GEV][136];
    __shared__ float gg[GEV][772];

    int cnt = *cnt_p;
    int e0 = blockIdx.x * GEV;
    if (e0 >= cnt) return;

    int tid = threadIdx.x;
    int ev = tid >> 4, c8 = (tid & 15) * 8;

    {   // stage: 16 threads per event, 8 channels each; zero-pad beyond cnt
        int e = e0 + ev;
        float4 a0, a1, c0, c1;
        if (e < cnt) {
            int t = order[e];
            int pu = prevu[t], pi = previ[t];
            const float* up = (pu < 0 ? U0 + (size_t)uids[t] * EMB : NUr + (size_t)pu * EMB) + c8;
            const float* vp = (pi < 0 ? V0 + (size_t)iids[t] * EMB : NVr + (size_t)pi * EMB) + c8;
            a0 = ((const float4*)up)[0]; a1 = ((const float4*)up)[1];
            c0 = ((const float4*)vp)[0]; c1 = ((const float4*)vp)[1];
        } else {
            a0 = make_float4(0.f, 0.f, 0.f, 0.f); a1 = a0; c0 = a0; c1 = a0;
        }
        *(ushort4*)&xbu[ev][c8]     = make_ushort4(f2bf(a0.x), f2bf(a0.y), f2bf(a0.z), f2bf(a0.w));
        *(ushort4*)&xbu[ev][c8 + 4] = make_ushort4(f2bf(a1.x), f2bf(a1.y), f2bf(a1.z), f2bf(a1.w));
        *(ushort4*)&xbv[ev][c8]     = make_ushort4(f2bf(c0.x), f2bf(c0.y), f2bf(c0.z), f2bf(c0.w));
        *(ushort4*)&xbv[ev][c8 + 4] = make_ushort4(f2bf(c1.x), f2bf(c1.y), f2bf(c1.z), f2bf(c1.w));
    }
    __syncthreads();

    int w = tid >> 6, l = tid & 63;
    int lr = l & 15, lk = (l >> 4) * 8;

    for (int ph = 0; ph < 2; ++ph) {
        const unsigned short* Wi = ph ? wb_ii : wb_ui;
        const unsigned short* Wh = ph ? wb_ih : wb_uh;
        const unsigned short (*Xi)[136] = ph ? xbu : xbv;
        const unsigned short (*Xh)[136] = ph ? xbv : xbu;

        f32x4 acc[12] = {};
        #pragma unroll
        for (int kk = 0; kk < 4; ++kk) {
            bf16x8 ai = *(const bf16x8*)&Xi[lr][kk * 32 + lk];
            bf16x8 ah = *(const bf16x8*)&Xh[lr][kk * 32 + lk];
            #pragma unroll
            for (int j = 0; j < 12; ++j) {
                int nt = w * 12 + j;
                bool ish = nt >= 24;
                int brow = (ish ? nt - 24 : nt) * 16 + lr;
                const unsigned short* W = ish ? Wh : Wi;
                bf16x8 b = *(const bf16x8*)(W + (size_t)brow * EMB + kk * 32 + lk);
                acc[j] = __builtin_amdgcn_mfma_f32_16x16x32_bf16(ish ? ah : ai, b, acc[j], 0, 0, 0);
            }
        }
        #pragma unroll
        for (int j = 0; j < 12; ++j) {
            int nt = w * 12 + j;
            #pragma unroll
            for (int i = 0; i < 4; ++i)
                gg[(l >> 4) * 4 + i][nt * 16 + lr] = acc[j][i];
        }
        __syncthreads();

        {   // combine (gg[ev][0..383]=gi, [384..767]=gh)
            int e = e0 + ev;
            if (e < cnt) {
                int t = order[e];
                const float* bi = ph ? bii : bui;
                const float* bh = ph ? bih : buh;
                float* N = ph ? NV : NU;
                const unsigned short (*xh)[136] = ph ? xbv : xbu;
                #pragma unroll
                for (int i = 0; i < 8; ++i) {
                    int ch = c8 + i;
                    float r_ = sigmoidf_(gg[ev][ch] + bi[ch] + gg[ev][384 + ch] + bh[ch]);
                    float z_ = sigmoidf_(gg[ev][128 + ch] + bi[128 + ch] + gg[ev][512 + ch] + bh[128 + ch]);
                    float n_ = tanhf(gg[ev][256 + ch] + bi[256 + ch] + r_ * (gg[ev][640 + ch] + bh[256 + ch]));
                    float h = bf2f(xh[ev][ch]);
                    N[(size_t)t * EMB + ch] = (1.f - z_) * n_ + z_ * h;
                }
            }
        }
        __syncthreads();
    }
}

// ---------------------------------------------------------------------------
// Kernel 4: lev>=2 events (~15), fp32, component-serial, 1024 threads.
// #pragma unroll 1 on the batch loop is LOAD-BEARING (rounds 5/6: full unroll
// -> 768 live regs -> scratch spill -> 100% spill-BW-bound).
// ---------------------------------------------------------------------------
__global__ __launch_bounds__(1024) void tail2_kernel(
    const float* __restrict__ U0,  const float* __restrict__ V0,
    const float* __restrict__ Wui, const float* __restrict__ Wuh,
    const float* __restrict__ bui, const float* __restrict__ buh,
    const float* __restrict__ Wii, const float* __restrict__ Wih,
    const float* __restrict__ bii, const float* __restrict__ bih,
    const int* __restrict__ uids,  const int* __restrict__ iids,
    const int* __restrict__ prevu, const int* __restrict__ previ,
    const int* __restrict__ tail2Order, const int* __restrict__ compStart,
    const Hdr* __restrict__ hdr,
    float* __restrict__ NU, float* __restrict__ NV)
{
    __shared__ __align__(16) float su[EMB];
    __shared__ __align__(16) float sv[EMB];
    __shared__ float gg[1536];
    int tid = threadIdx.x;
    int ncomp = hdr->ncomp2;

    int g = tid >> 4, j = tid & 15;
    int mat = g >> 4;
    const float* W = (mat == 0) ? Wui : (mat == 1) ? Wuh : (mat == 2) ? Wii : Wih;

    for (int c = blockIdx.x; c < ncomp; c += gridDim.x) {
        int kb = compStart[c], ke = compStart[c + 1];
        for (int k = kb; k < ke; ++k) {
            int t = tail2Order[k];
            int pu = prevu[t], pi = previ[t];
            const float* up = (pu < 0) ? U0 + (size_t)uids[t] * EMB : NU + (size_t)pu * EMB;
            const float* vp = (pi < 0) ? V0 + (size_t)iids[t] * EMB : NV + (size_t)pi * EMB;
            __syncthreads();
            if (tid < EMB)        su[tid] = up[tid];
            else if (tid < 2*EMB) sv[tid - EMB] = vp[tid - EMB];
            __syncthreads();

            const float* x = (mat == 1 || mat == 2) ? su : sv;
            const float4* x4 = (const float4*)x;
            float4 xa = x4[2 * j], xb = x4[2 * j + 1];
            #pragma unroll 1
            for (int b = 0; b < 3; ++b) {
                int rbase = (g & 15) * 24 + b * 8;
                float4 w0[8], w1[8];
                #pragma unroll
                for (int q = 0; q < 8; ++q) {
                    const float4* W4 = (const float4*)(W + (size_t)(rbase + q) * EMB);
                    w0[q] = W4[2 * j]; w1[q] = W4[2 * j + 1];
                }
                #pragma unroll
                for (int q = 0; q < 8; ++q) {
                    float s = w0[q].x * xa.x + w0[q].y * xa.y
                            + w0[q].z * xa.z + w0[q].w * xa.w
                            + w1[q].x * xb.x + w1[q].y * xb.y
                            + w1[q].z * xb.z + w1[q].w * xb.w;
                    s += __shfl_xor(s, 1); s += __shfl_xor(s, 2);
                    s += __shfl_xor(s, 4); s += __shfl_xor(s, 8);
                    if (j == q) gg[mat * 384 + rbase + q] = s;
                }
            }
            __syncthreads();

            if (tid < EMB) {
                int e = tid;
                float r_ = sigmoidf_(gg[e] + bui[e] + gg[384 + e] + buh[e]);
                float z_ = sigmoidf_(gg[128 + e] + bui[128 + e] + gg[512 + e] + buh[128 + e]);
                float n_ = tanhf(gg[256 + e] + bui[256 + e] + r_ * (gg[640 + e] + buh[256 + e]));
                NU[(size_t)t * EMB + e] = (1.f - z_) * n_ + z_ * su[e];
            } else if (tid < 2*EMB) {
                int e = tid - EMB;
                float r_ = sigmoidf_(gg[768 + e] + bii[e] + gg[1152 + e] + bih[e]);
                float z_ = sigmoidf_(gg[896 + e] + bii[128 + e] + gg[1280 + e] + bih[128 + e]);
                float n_ = tanhf(gg[1024 + e] + bii[256 + e] + r_ * (gg[1408 + e] + bih[256 + e]));
                NV[(size_t)t * EMB + e] = (1.f - z_) * n_ + z_ * sv[e];
            }
        }
    }
}

// ---------------------------------------------------------------------------
// Kernel 5 (FUSED post): gather+loss -> T1 MFMA -> h1(bf16,LDS) -> T2 MFMA
// -> T3+sigmoid. Block = 64 events, 4 waves. No H1/XA global round-trips.
// ---------------------------------------------------------------------------
__global__ __launch_bounds__(256) void post_fused_kernel(
    const float* __restrict__ U0, const float* __restrict__ V0,
    const int* __restrict__ uids, const int* __restrict__ iids,
    const int* __restrict__ prevu, const int* __restrict__ previ,
    const float* __restrict__ NU, const float* __restrict__ NV,
    const unsigned short* __restrict__ t1wb, const float* __restrict__ T1b,
    const unsigned short* __restrict__ t2wb, const float* __restrict__ T2b,
    const float* __restrict__ T3w, const float* __restrict__ T3b,
    float* __restrict__ out, int nev)
{
    __shared__ __align__(16) unsigned short xau[64][136];   // 17.4 KB
    __shared__ __align__(16) unsigned short xav[64][136];   // 17.4 KB
    __shared__ __align__(16) unsigned short h1b[64][136];   // 17.4 KB
    __shared__ float h2s[64][36];                           //  9.2 KB

    int tid = threadIdx.x;
    int ev0 = blockIdx.x * 64;

    // ---- stage (bf16) + loss ----
    #pragma unroll
    for (int rep = 0; rep < 4; ++rep) {
        int idx = rep * 256 + tid;            // 0..1023
        int evl = idx >> 4, j16 = idx & 15;
        int t = ev0 + evl;
        float4 a0, a1, c0, c1;
        if (t < nev) {
            int pu = prevu[t], pi = previ[t];
            const float* up = (pu < 0 ? U0 + (size_t)uids[t] * EMB : NU + (size_t)pu * EMB) + j16 * 8;
            const float* vp = (pi < 0 ? V0 + (size_t)iids[t] * EMB : NV + (size_t)pi * EMB) + j16 * 8;
            a0 = ((const float4*)up)[0]; a1 = ((const float4*)up)[1];
            c0 = ((const float4*)vp)[0]; c1 = ((const float4*)vp)[1];
        } else {
            a0 = make_float4(0.f, 0.f, 0.f, 0.f); a1 = a0; c0 = a0; c1 = a0;
        }
        *(ushort4*)&xau[evl][j16 * 8]     = make_ushort4(f2bf(a0.x), f2bf(a0.y), f2bf(a0.z), f2bf(a0.w));
        *(ushort4*)&xau[evl][j16 * 8 + 4] = make_ushort4(f2bf(a1.x), f2bf(a1.y), f2bf(a1.z), f2bf(a1.w));
        *(ushort4*)&xav[evl][j16 * 8]     = make_ushort4(f2bf(c0.x), f2bf(c0.y), f2bf(c0.z), f2bf(c0.w));
        *(ushort4*)&xav[evl][j16 * 8 + 4] = make_ushort4(f2bf(c1.x), f2bf(c1.y), f2bf(c1.z), f2bf(c1.w));
        float dp = a0.x * c0.x + a0.y * c0.y + a0.z * c0.z + a0.w * c0.w
                 + a1.x * c1.x + a1.y * c1.y + a1.z * c1.z + a1.w * c1.w;
        dp += __shfl_xor(dp, 1); dp += __shfl_xor(dp, 2);
        dp += __shfl_xor(dp, 4); dp += __shfl_xor(dp, 8);
        if (j16 == 0 && t < nev)
            out[2 * (size_t)t] = -logf(softplusf_(dp) + 1e-10f);
    }
    __syncthreads();

    int w = tid >> 6, l = tid & 63;
    int lr = l & 15, lk = (l >> 4) * 8;

    // ---- T1: 128 cols, K=256 ([u|v]) ----
    {
        f32x4 acc[8] = {};
        #pragma unroll
        for (int kh = 0; kh < 8; ++kh) {
            const unsigned short* ar = (kh < 4)
                ? &xau[w * 16 + lr][kh * 32 + lk]
                : &xav[w * 16 + lr][(kh - 4) * 32 + lk];
            bf16x8 a = *(const bf16x8*)ar;
            #pragma unroll
            for (int n = 0; n < 8; ++n) {
                bf16x8 b = *(const bf16x8*)(t1wb + (size_t)(n * 16 + lr) * 256 + kh * 32 + lk);
                acc[n] = __builtin_amdgcn_mfma_f32_16x16x32_bf16(a, b, acc[n], 0, 0, 0);
            }
        }
        #pragma unroll
        for (int n = 0; n < 8; ++n) {
            int col = n * 16 + lr;
            float bb = T1b[col];
            #pragma unroll
            for (int i = 0; i < 4; ++i)
                h1b[w * 16 + (l >> 4) * 4 + i][col] = f2bf(fmaxf(acc[n][i] + bb, 0.f));
        }
    }
    __syncthreads();

    // ---- T2: 32 cols, K=128 ----
    {
        f32x4 acc2[2] = {};
        #pragma unroll
        for (int kk = 0; kk < 4; ++kk) {
            bf16x8 a = *(const bf16x8*)&h1b[w * 16 + lr][kk * 32 + lk];
            #pragma unroll
            for (int n = 0; n < 2; ++n) {
                bf16x8 b = *(const bf16x8*)(t2wb + (size_t)(n * 16 + lr) * 128 + kk * 32 + lk);
                acc2[n] = __builtin_amdgcn_mfma_f32_16x16x32_bf16(a, b, acc2[n], 0, 0, 0);
            }
        }
        #pragma unroll
        for (int n = 0; n < 2; ++n) {
            int col = n * 16 + lr;
            float bb = T2b[col];
            #pragma unroll
            for (int i = 0; i < 4; ++i)
                h2s[w * 16 + (l >> 4) * 4 + i][col] = fmaxf(acc2[n][i] + bb, 0.f);
        }
    }
    __syncthreads();

    // ---- T3 + sigmoid: 4 lanes per event, 8 channels each ----
    {
        int evl = tid >> 2, q4 = tid & 3;
        float p = 0.f;
        #pragma unroll
        for (int i = 0; i < 8; ++i) {
            int ch = q4 * 8 + i;
            p = fmaf(T3w[ch], h2s[evl][ch], p);
        }
        p += __shfl_xor(p, 1); p += __shfl_xor(p, 2);
        int t = ev0 + evl;
        if (q4 == 0 && t < nev)
            out[2 * (size_t)t + 1] = sigmoidf_(p + T3b[0]);
    }
}

// ---------------------------------------------------------------------------
extern "C" void kernel_launch(void* const* d_in, const int* in_sizes, int n_in,
                              void* d_out, int out_size, void* d_ws, size_t ws_size,
                              hipStream_t stream)
{
    const float* U0  = (const float*)d_in[0];
    const float* V0  = (const float*)d_in[1];
    const float* Wui = (const float*)d_in[2];
    const float* Wuh = (const float*)d_in[3];
    const float* bui = (const float*)d_in[4];
    const float* buh = (const float*)d_in[5];
    const float* Wii = (const float*)d_in[6];
    const float* Wih = (const float*)d_in[7];
    const float* bii = (const float*)d_in[8];
    const float* bih = (const float*)d_in[9];
    const float* T1w = (const float*)d_in[10];
    const float* T1b = (const float*)d_in[11];
    const float* T2w = (const float*)d_in[12];
    const float* T2b = (const float*)d_in[13];
    const float* T3w = (const float*)d_in[14];
    const float* T3b = (const float*)d_in[15];
    const int* uids  = (const int*)d_in[16];
    const int* iids  = (const int*)d_in[17];
    int nev = in_sizes[16];

    char* ws = (char*)d_ws;
    int* base = (int*)ws;
    int* prevu      = base;                 // MAXEV
    int* previ      = base + MAXEV;         // MAXEV
    int* order0     = base + 2 * MAXEV;     // MAXEV
    int* order1     = base + 3 * MAXEV;     // MAXEV
    int* tail2Order = base + 4 * MAXEV;     // MAXEV
    int* compStart  = base + 5 * MAXEV;     // MAXEV+2
    Hdr* hdr        = (Hdr*)(base + 6 * MAXEV + 4);
    float* NU = (float*)(ws + (160 << 10));              // 2 MB
    float* NV = NU + (size_t)MAXEV * EMB;                // 2 MB
    unsigned short* wb_uh = (unsigned short*)(NV + (size_t)MAXEV * EMB);
    unsigned short* wb_ii = wb_uh + 384 * EMB;           // 96 KB each
    unsigned short* wb_ui = wb_ii + 384 * EMB;
    unsigned short* wb_ih = wb_ui + 384 * EMB;
    unsigned short* t1wb  = wb_ih + 384 * EMB;           // 64 KB
    unsigned short* t2wb  = t1wb + EMB * 256;            // 8 KB
    float* out = (float*)d_out;

    prev_kernel<<<MAXEV, 64, 0, stream>>>(
        uids, iids, prevu, previ, nev,
        Wuh, Wii, Wui, Wih, T1w, T2w,
        wb_uh, wb_ii, wb_ui, wb_ih, t1wb, t2wb);
    setup_kernel<<<1, 1024, 0, stream>>>(prevu, previ, order0, order1,
                                         tail2Order, compStart, hdr, nev);

    // Pass A: level-0 events (fused gather + gate MFMA + combine)
    gru_fused_kernel<<<MAXEV / GEV, 256, 0, stream>>>(
        U0, V0, wb_ui, wb_uh, wb_ii, wb_ih, bui, buh, bii, bih,
        uids, iids, prevu, previ, NU, NV, order0, &hdr->nl0, NU, NV);

    // Pass B: level-1 events (preds all level-0, visible by stream order)
    gru_fused_kernel<<<MAXEV / GEV, 256, 0, stream>>>(
        U0, V0, wb_ui, wb_uh, wb_ii, wb_ih, bui, buh, bii, bih,
        uids, iids, prevu, previ, NU, NV, order1, &hdr->nl1, NU, NV);

    // lev>=2 remainder: component-serial
    tail2_kernel<<<64, 1024, 0, stream>>>(
        U0, V0, Wui, Wuh, bui, buh, Wii, Wih, bii, bih,
        uids, iids, prevu, previ, tail2Order, compStart, hdr, NU, NV);

    // fused loss + MLP branch
    post_fused_kernel<<<(nev + 63) / 64, 256, 0, stream>>>(
        U0, V0, uids, iids, prevu, previ, NU, NV,
        t1wb, T1b, t2wb, T2b, T3w, T3b, out, nev);
}